// Round 11
// baseline (608.815 us; speedup 1.0000x reference)
//
#include <hip/hip_runtime.h>
#include <hip/hip_bf16.h>

// Harness-provided kernel symbol kept (not required to do work).
__global__ void GraphEncoder_20555713479231_kernel() {}

__device__ __forceinline__ float bf2f_lo(unsigned u) { return __uint_as_float(u << 16); }
__device__ __forceinline__ float bf2f_hi(unsigned u) { return __uint_as_float(u & 0xffff0000u); }
__device__ __forceinline__ unsigned short f2bf(float f) {
  unsigned u = __float_as_uint(f);
  return (unsigned short)((u + 0x7fffu + ((u >> 16) & 1u)) >> 16);
}
__device__ __forceinline__ unsigned packbf(float a, float b) {
  return (unsigned)f2bf(a) | ((unsigned)f2bf(b) << 16);
}

// ---------------- CSR build ----------------
__global__ __launch_bounds__(256) void k_zero(int* __restrict__ p, int n) {
  int i = blockIdx.x * blockDim.x + threadIdx.x;
  if (i < n) p[i] = 0;
}

__global__ __launch_bounds__(256) void k_hist(const int* __restrict__ dst,
                                              int* __restrict__ deg, int e) {
  int i = blockIdx.x * blockDim.x + threadIdx.x;
  if (i < e) atomicAdd(&deg[dst[i]], 1);
}

// parallel scan pass 1: per-block exclusive scan of (deg[i]+1); block totals to bsum
__global__ __launch_bounds__(256) void k_scan1(const int* __restrict__ deg,
                                               int* __restrict__ off,
                                               int* __restrict__ bsum, int n) {
  __shared__ int wsum[4];
  int tid = threadIdx.x;
  int gid = blockIdx.x * 256 + tid;
  int lane = tid & 63, wid = tid >> 6;
  int v = (gid < n) ? (deg[gid] + 1) : 0;
  int x = v;
  #pragma unroll
  for (int d = 1; d < 64; d <<= 1) {
    int t = __shfl_up(x, d);
    if (lane >= d) x += t;
  }
  if (lane == 63) wsum[wid] = x;
  __syncthreads();
  int wpre = 0;
  for (int k = 0; k < wid; ++k) wpre += wsum[k];
  if (gid < n) off[gid] = wpre + x - v;
  if (tid == 0) {
    int t = 0;
    #pragma unroll
    for (int k = 0; k < 4; ++k) t += wsum[k];
    bsum[blockIdx.x] = t;
  }
}

// pass 2: single block scans block sums (nb <= 256) exclusive; total -> off[n]
__global__ __launch_bounds__(256) void k_scan2(int* __restrict__ bsum,
                                               int* __restrict__ off, int nb, int n) {
  __shared__ int wsum[4];
  int tid = threadIdx.x;
  int lane = tid & 63, wid = tid >> 6;
  int v = (tid < nb) ? bsum[tid] : 0;
  int x = v;
  #pragma unroll
  for (int d = 1; d < 64; d <<= 1) {
    int t = __shfl_up(x, d);
    if (lane >= d) x += t;
  }
  if (lane == 63) wsum[wid] = x;
  __syncthreads();
  int wpre = 0;
  for (int k = 0; k < wid; ++k) wpre += wsum[k];
  if (tid < nb) bsum[tid] = wpre + x - v;
  if (tid == 0) {
    int t = 0;
    #pragma unroll
    for (int k = 0; k < 4; ++k) t += wsum[k];
    off[n] = t;
  }
}

// pass 3: add block prefix
__global__ __launch_bounds__(256) void k_scan3(int* __restrict__ off,
                                               const int* __restrict__ bsum, int n) {
  int gid = blockIdx.x * 256 + threadIdx.x;
  if (gid < n) off[gid] += bsum[blockIdx.x];
}

__global__ __launch_bounds__(256) void k_initpos(const int* __restrict__ off,
                                                 int* __restrict__ pos,
                                                 int* __restrict__ csr, int n) {
  int i = blockIdx.x * blockDim.x + threadIdx.x;
  if (i < n) {
    int o = off[i];
    csr[o] = i;  // self-loop occupies first slot
    pos[i] = o + 1;
  }
}

__global__ __launch_bounds__(256) void k_fill(const int* __restrict__ src,
                                              const int* __restrict__ dst,
                                              int* __restrict__ pos,
                                              int* __restrict__ csr, int e) {
  int i = blockIdx.x * blockDim.x + threadIdx.x;
  if (i < e) {
    int d = dst[i];
    int p = atomicAdd(&pos[d], 1);
    csr[p] = src[i];
  }
}

// ---------------- layer 0: emb @ W (3x16 @ 16x128) tables ----------------
// tlb: packed bf16 pairs (3 x 64 uints); trf: f32 (3 x 128)
__global__ __launch_bounds__(256) void k_embw(const float* __restrict__ emb,
                                              const float* __restrict__ wl,
                                              const float* __restrict__ wr,
                                              unsigned* __restrict__ tlb,
                                              float* __restrict__ trf) {
  int tid = threadIdx.x;
  if (tid >= 192) return;
  int row = tid >> 6, cp = tid & 63, c0 = cp * 2;
  float al0 = 0.f, al1 = 0.f, ar0 = 0.f, ar1 = 0.f;
  #pragma unroll
  for (int k = 0; k < 16; ++k) {
    float ev = emb[row * 16 + k];
    al0 += ev * wl[k * 128 + c0];
    al1 += ev * wl[k * 128 + c0 + 1];
    ar0 += ev * wr[k * 128 + c0];
    ar1 += ev * wr[k * 128 + c0 + 1];
  }
  tlb[row * 64 + cp] = packbf(al0, al1);
  *(float2*)(trf + row * 128 + c0) = make_float2(ar0, ar1);
}

// ---------------- layer-0 aggregation via neighbor-type histogram ----------------
__global__ __launch_bounds__(256)
void k_agg0(const int* __restrict__ off, const int* __restrict__ csr,
            const int* __restrict__ types,
            const unsigned* __restrict__ tlb, const float* __restrict__ trf,
            const float* __restrict__ att, const float* __restrict__ bias,
            const float* __restrict__ lng, const float* __restrict__ lnb,
            unsigned* __restrict__ yout, int n) {
  int v = (blockIdx.x * blockDim.x + threadIdx.x) >> 6;
  int lane = threadIdx.x & 63;
  if (v >= n) return;
  v = __builtin_amdgcn_readfirstlane(v);
  int beg = off[v], end = off[v + 1];
  int c0 = 0, c1 = 0, c2 = 0;
  for (int base = beg; base < end; base += 64) {
    int e = base + lane;
    bool act = e < end;
    int u = act ? csr[e] : 0;
    int ty = act ? types[u] : 3;
    c0 += __popcll(__ballot(ty == 0));
    c1 += __popcll(__ballot(ty == 1));
    c2 += __popcll(__ballot(ty == 2));
  }
  float cnt[3] = {(float)c0, (float)c1, (float)c2};
  int f0 = lane * 2;
  int tyv = types[v];
  float2 xrv = *(const float2*)(trf + tyv * 128 + f0);
  float a0 = att[f0], a1 = att[f0 + 1];
  float s = 0.f, O0 = 0.f, O1 = 0.f;
  #pragma unroll
  for (int ty = 0; ty < 3; ++ty) {
    unsigned p = tlb[ty * 64 + lane];
    float x0 = bf2f_lo(p), x1 = bf2f_hi(p);
    float t0 = x0 + xrv.x; t0 = t0 > 0.f ? t0 : 0.2f * t0;
    float t1 = x1 + xrv.y; t1 = t1 > 0.f ? t1 : 0.2f * t1;
    float c = t0 * a0 + t1 * a1;
    c += __shfl_xor(c, 1);
    c += __shfl_xor(c, 2);
    c += __shfl_xor(c, 4);
    c += __shfl_xor(c, 8);
    float w = cnt[ty] * __expf(c);
    s += w;
    O0 = fmaf(w, x0, O0);
    O1 = fmaf(w, x1, O1);
  }
  float inv = 1.f / s;
  float o0 = O0 * inv + bias[f0];
  float o1 = O1 * inv + bias[f0 + 1];
  float sum = o0 + o1, sq = o0 * o0 + o1 * o1;
  #pragma unroll
  for (int d2 = 1; d2 < 64; d2 <<= 1) {
    sum += __shfl_xor(sum, d2);
    sq += __shfl_xor(sq, d2);
  }
  float mu = sum * (1.f / 128.f);
  float var = sq * (1.f / 128.f) - mu * mu;
  float rstd = rsqrtf(var + 1e-5f);
  float y0 = fmaxf((o0 - mu) * rstd * lng[f0] + lnb[f0], 0.f);
  float y1 = fmaxf((o1 - mu) * rstd * lng[f0 + 1] + lnb[f0 + 1], 0.f);
  yout[(size_t)v * 64 + lane] = packbf(y0, y1);
}

// ---------------- GEMM (VALU, LDS-tiled): x(Nx128 bf16) @ [Wl|Wr](128x256) ----------
__global__ __launch_bounds__(256)
void k_gemm(const unsigned* __restrict__ x,
            const float* __restrict__ wl,
            const float* __restrict__ wr,
            unsigned* __restrict__ xlo, unsigned* __restrict__ xro, int n) {
  __shared__ float xsh[32 * 128];  // [row][k]   16 KB (unpacked to f32 at staging)
  __shared__ float wsh[32 * 256];  // [kk][col]  32 KB  (col<128 Wl, col>=128 Wr)
  int tid = threadIdx.x;
  int r0 = blockIdx.x * 32;
  #pragma unroll
  for (int i = 0; i < 8; ++i) {
    int j = i * 256 + tid;  // uint idx 0..2047: row = j>>6, kp = j&63
    int rr = r0 + (j >> 6);
    unsigned p = 0;
    if (rr < n) p = x[(size_t)rr * 64 + (j & 63)];
    *(float2*)(xsh + (j >> 6) * 128 + (j & 63) * 2) = make_float2(bf2f_lo(p), bf2f_hi(p));
  }
  int rg = tid >> 5;
  int cq = tid & 31;
  int cL = cq * 4;
  float acc[4][8];  // [row][0..3 = Wl cols cL.., 4..7 = Wr cols cL..]
  #pragma unroll
  for (int a = 0; a < 4; ++a)
    #pragma unroll
    for (int b = 0; b < 8; ++b) acc[a][b] = 0.f;
  for (int kc = 0; kc < 4; ++kc) {
    __syncthreads();
    #pragma unroll
    for (int i = 0; i < 8; ++i) {
      int j = i * 256 + tid;  // float4 idx: kk = j>>6, c = (j&63)*4
      int kk = j >> 6;
      int c = (j & 63) * 4;
      int k = kc * 32 + kk;
      float4 v = (c < 128) ? *(const float4*)(wl + (size_t)k * 128 + c)
                           : *(const float4*)(wr + (size_t)k * 128 + (c - 128));
      *(float4*)(wsh + kk * 256 + c) = v;
    }
    __syncthreads();
    #pragma unroll 4
    for (int kk = 0; kk < 32; ++kk) {
      float xv[4];
      #pragma unroll
      for (int a = 0; a < 4; ++a) xv[a] = xsh[(rg * 4 + a) * 128 + kc * 32 + kk];
      float4 w0 = *(float4*)(wsh + kk * 256 + cL);
      float4 w1 = *(float4*)(wsh + kk * 256 + 128 + cL);
      #pragma unroll
      for (int a = 0; a < 4; ++a) {
        acc[a][0] += xv[a] * w0.x; acc[a][1] += xv[a] * w0.y;
        acc[a][2] += xv[a] * w0.z; acc[a][3] += xv[a] * w0.w;
        acc[a][4] += xv[a] * w1.x; acc[a][5] += xv[a] * w1.y;
        acc[a][6] += xv[a] * w1.z; acc[a][7] += xv[a] * w1.w;
      }
    }
  }
  #pragma unroll
  for (int a = 0; a < 4; ++a) {
    int rr = r0 + rg * 4 + a;
    if (rr < n) {
      uint2 pk, pr;
      pk.x = packbf(acc[a][0], acc[a][1]);
      pk.y = packbf(acc[a][2], acc[a][3]);
      pr.x = packbf(acc[a][4], acc[a][5]);
      pr.y = packbf(acc[a][6], acc[a][7]);
      *(uint2*)(xlo + (size_t)rr * 64 + (cL >> 1)) = pk;
      *(uint2*)(xro + (size_t)rr * 64 + (cL >> 1)) = pr;
    }
  }
}

// ---------------- fused aggregate + bias + residual + LN + ReLU ----------------
// TWO waves per dst node (even/odd edge interleave) to double memory-level
// parallelism; partial sums (s,O0,O1 -- associative, no-max softmax) combined
// through LDS; subwave 0 runs the epilogue. Lane owns features 2*lane, 2*lane+1.
__global__ __launch_bounds__(256)
void k_agg(const int* __restrict__ off, const int* __restrict__ csr,
           const unsigned* __restrict__ xl, const unsigned* __restrict__ xr,
           const float* __restrict__ att, const float* __restrict__ bias,
           const unsigned* __restrict__ xres,
           const float* __restrict__ lng, const float* __restrict__ lnb,
           unsigned* __restrict__ ybf, float* __restrict__ yf32, int n, int wide) {
  __shared__ float part[2][3][64];  // [node slot][s,O0,O1][lane]
  int tid = threadIdx.x;
  int lane = tid & 63;
  int waveid = tid >> 6;
  int half = waveid & 1;   // subwave within node
  int slot = waveid >> 1;  // node slot within block
  int v = blockIdx.x * 2 + slot;
  bool act = v < n;
  int f0 = lane * 2;
  float sa = 0.f, Oa0 = 0.f, Oa1 = 0.f;
  float sb = 0.f, Ob0 = 0.f, Ob1 = 0.f;
  float r0 = 0.f, r1 = 0.f, a0 = 0.f, a1 = 0.f;
  int beg = 0, end = 0;
  if (act) {
    int vv = __builtin_amdgcn_readfirstlane(v);
    a0 = att[f0]; a1 = att[f0 + 1];
    unsigned rv = xr[(size_t)vv * 64 + lane];
    r0 = bf2f_lo(rv); r1 = bf2f_hi(rv);
    beg = off[vv]; end = off[vv + 1];
    int last = end - 1;
    const unsigned* xlp = xl + lane;  // row r at xlp[r*64]
    int e0 = beg + half;              // this wave: e0, e0+2, e0+4, ...
    int iA = csr[min(e0, last)];
    int iB = csr[min(e0 + 2, last)];
    int iC = csr[min(e0 + 4, last)];
    int iD = csr[min(e0 + 6, last)];
    unsigned pA = xlp[(size_t)iA * 64];
    unsigned pB = xlp[(size_t)iB * 64];
    unsigned pC = xlp[(size_t)iC * 64];
    unsigned pD = xlp[(size_t)iD * 64];
    for (int e = e0; e < end; e += 4) {
      int i4 = csr[min(e + 8, last)];
      int i5 = csr[min(e + 10, last)];
      unsigned p4 = xlp[(size_t)i4 * 64];
      unsigned p5 = xlp[(size_t)i5 * 64];
      float x0a = bf2f_lo(pA), x1a = bf2f_hi(pA);
      float x0b = bf2f_lo(pB), x1b = bf2f_hi(pB);
      float t0a = x0a + r0; t0a = t0a > 0.f ? t0a : 0.2f * t0a;
      float t1a = x1a + r1; t1a = t1a > 0.f ? t1a : 0.2f * t1a;
      float t0b = x0b + r0; t0b = t0b > 0.f ? t0b : 0.2f * t0b;
      float t1b = x1b + r1; t1b = t1b > 0.f ? t1b : 0.2f * t1b;
      float ca = t0a * a0 + t1a * a1;
      float cb = t0b * a0 + t1b * a1;
      ca += __shfl_xor(ca, 1); cb += __shfl_xor(cb, 1);
      ca += __shfl_xor(ca, 2); cb += __shfl_xor(cb, 2);
      ca += __shfl_xor(ca, 4); cb += __shfl_xor(cb, 4);
      ca += __shfl_xor(ca, 8); cb += __shfl_xor(cb, 8);
      if (wide) {
        ca += __shfl_xor(ca, 16); cb += __shfl_xor(cb, 16);
        ca += __shfl_xor(ca, 32); cb += __shfl_xor(cb, 32);
      }
      float wa = __expf(ca);
      float wb = (e + 2 < end) ? __expf(cb) : 0.f;
      sa += wa; Oa0 = fmaf(wa, x0a, Oa0); Oa1 = fmaf(wa, x1a, Oa1);
      sb += wb; Ob0 = fmaf(wb, x0b, Ob0); Ob1 = fmaf(wb, x1b, Ob1);
      pA = pC; pB = pD; pC = p4; pD = p5;
    }
  }
  float s = sa + sb, O0 = Oa0 + Ob0, O1 = Oa1 + Ob1;
  if (half == 1) {
    part[slot][0][lane] = s;
    part[slot][1][lane] = O0;
    part[slot][2][lane] = O1;
  }
  __syncthreads();
  if (half == 1 || !act) return;
  s += part[slot][0][lane];
  O0 += part[slot][1][lane];
  O1 += part[slot][2][lane];
  int vv = __builtin_amdgcn_readfirstlane(v);
  float inv = 1.f / s;
  float o0 = O0 * inv + bias[f0];
  float o1 = O1 * inv + bias[f0 + 1];
  if (xres) {
    unsigned rs = xres[(size_t)vv * 64 + lane];
    o0 += bf2f_lo(rs);
    o1 += bf2f_hi(rs);
  }
  float sum = o0 + o1, sq = o0 * o0 + o1 * o1;
  #pragma unroll
  for (int d2 = 1; d2 < 64; d2 <<= 1) {
    sum += __shfl_xor(sum, d2);
    sq += __shfl_xor(sq, d2);
  }
  float mu = sum * (1.f / 128.f);
  float var = sq * (1.f / 128.f) - mu * mu;
  float rstd = rsqrtf(var + 1e-5f);
  float y0 = fmaxf((o0 - mu) * rstd * lng[f0] + lnb[f0], 0.f);
  float y1 = fmaxf((o1 - mu) * rstd * lng[f0 + 1] + lnb[f0 + 1], 0.f);
  if (yf32) {
    *(float2*)(yf32 + (size_t)vv * 128 + f0) = make_float2(y0, y1);
  } else {
    ybf[(size_t)vv * 64 + lane] = packbf(y0, y1);
  }
}

// ---------------- launch ----------------
extern "C" void kernel_launch(void* const* d_in, const int* in_sizes, int n_in,
                              void* d_out, int out_size, void* d_ws, size_t ws_size,
                              hipStream_t stream) {
  (void)n_in; (void)out_size; (void)ws_size;
  const int* node_types = (const int*)d_in[0];
  const int* edge_index = (const int*)d_in[1];
  const float* emb = (const float*)d_in[2];
  const float* Wl0 = (const float*)d_in[3];
  const float* Wr0 = (const float*)d_in[4];
  const float* att0 = (const float*)d_in[5];
  const float* b0 = (const float*)d_in[6];
  const float* Wl1 = (const float*)d_in[7];
  const float* Wr1 = (const float*)d_in[8];
  const float* att1 = (const float*)d_in[9];
  const float* b1 = (const float*)d_in[10];
  const float* Wl2 = (const float*)d_in[11];
  const float* Wr2 = (const float*)d_in[12];
  const float* att2 = (const float*)d_in[13];
  const float* b2 = (const float*)d_in[14];
  const float* Wl3 = (const float*)d_in[15];
  const float* Wr3 = (const float*)d_in[16];
  const float* att3 = (const float*)d_in[17];
  const float* b3 = (const float*)d_in[18];
  const float* lng = (const float*)d_in[19];
  const float* lnb = (const float*)d_in[20];

  int n = in_sizes[0];
  int e = in_sizes[1] / 2;
  const int* srcp = edge_index;
  const int* dstp = edge_index + e;
  int nblocks = (n + 255) / 256;

  // workspace carve (256-byte aligned chunks)
  char* wsp = (char*)d_ws;
  size_t ofs = 0;
  int* deg = (int*)(wsp + ofs); ofs += (((size_t)n * 4) + 255) & ~(size_t)255;
  int* off = (int*)(wsp + ofs); ofs += (((size_t)(n + 1) * 4) + 255) & ~(size_t)255;
  int* csr = (int*)(wsp + ofs); ofs += (((size_t)(e + n) * 4) + 255) & ~(size_t)255;
  int* bsum = (int*)(wsp + ofs); ofs += (((size_t)nblocks * 4) + 255) & ~(size_t)255;
  unsigned* xlb = (unsigned*)(wsp + ofs); ofs += (((size_t)n * 64 * 4) + 255) & ~(size_t)255;
  unsigned* xrb = (unsigned*)(wsp + ofs); ofs += (((size_t)n * 64 * 4) + 255) & ~(size_t)255;
  unsigned* xcur = (unsigned*)(wsp + ofs); ofs += (((size_t)n * 64 * 4) + 255) & ~(size_t)255;
  unsigned* tlb = (unsigned*)(wsp + ofs); ofs += 1024;
  float* trf = (float*)(wsp + ofs); ofs += 2048;
  int* pos = deg;  // deg dead after scan; reuse as fill cursor

  // CSR build (graph identical across all 4 layers)
  k_zero<<<nblocks, 256, 0, stream>>>(deg, n);
  k_hist<<<(e + 255) / 256, 256, 0, stream>>>(dstp, deg, e);
  k_scan1<<<nblocks, 256, 0, stream>>>(deg, off, bsum, n);
  k_scan2<<<1, 256, 0, stream>>>(bsum, off, nblocks, n);
  k_scan3<<<nblocks, 256, 0, stream>>>(off, bsum, n);
  k_initpos<<<nblocks, 256, 0, stream>>>(off, pos, csr, n);
  k_fill<<<(e + 255) / 256, 256, 0, stream>>>(srcp, dstp, pos, csr, e);

  int aggBlocks = (n * 64 + 255) / 256;   // one wave per node (k_agg0)
  int aggBlocks2 = (n + 1) / 2;           // two waves per node (k_agg)

  // layer 0: type-table aggregation (ballot histogram; writes bf16 xcur)
  k_embw<<<1, 256, 0, stream>>>(emb, Wl0, Wr0, tlb, trf);
  k_agg0<<<aggBlocks, 256, 0, stream>>>(off, csr, node_types, tlb, trf,
                                        att0, b0, lng, lnb, xcur, n);

  int gemmBlocks = (n + 31) / 32;

  // layer 1
  k_gemm<<<gemmBlocks, 256, 0, stream>>>(xcur, Wl1, Wr1, xlb, xrb, n);
  k_agg<<<aggBlocks2, 256, 0, stream>>>(off, csr, xlb, xrb, att1, b1, xcur,
                                        lng + 128, lnb + 128, xcur, (float*)0, n, 0);
  // layer 2
  k_gemm<<<gemmBlocks, 256, 0, stream>>>(xcur, Wl2, Wr2, xlb, xrb, n);
  k_agg<<<aggBlocks2, 256, 0, stream>>>(off, csr, xlb, xrb, att2, b2, xcur,
                                        lng + 256, lnb + 256, xcur, (float*)0, n, 0);
  // layer 3 (single head, wide reduce; f32 output to d_out)
  k_gemm<<<gemmBlocks, 256, 0, stream>>>(xcur, Wl3, Wr3, xlb, xrb, n);
  k_agg<<<aggBlocks2, 256, 0, stream>>>(off, csr, xlb, xrb, att3, b3, xcur,
                                        lng + 384, lnb + 384, (unsigned*)0, (float*)d_out, n, 1);
}

// Round 12
// 446.275 us; speedup vs baseline: 1.3642x; 1.3642x over previous
//
#include <hip/hip_runtime.h>
#include <hip/hip_bf16.h>

// Harness-provided kernel symbol kept (not required to do work).
__global__ void GraphEncoder_20555713479231_kernel() {}

using bfrag8 = __attribute__((ext_vector_type(8))) short;  // 8 bf16 (4 VGPRs)
using facc4  = __attribute__((ext_vector_type(4))) float;  // 4 fp32 acc

__device__ __forceinline__ float bf2f_lo(unsigned u) { return __uint_as_float(u << 16); }
__device__ __forceinline__ float bf2f_hi(unsigned u) { return __uint_as_float(u & 0xffff0000u); }
__device__ __forceinline__ unsigned short f2bf(float f) {
  unsigned u = __float_as_uint(f);
  return (unsigned short)((u + 0x7fffu + ((u >> 16) & 1u)) >> 16);
}
__device__ __forceinline__ unsigned packbf(float a, float b) {
  return (unsigned)f2bf(a) | ((unsigned)f2bf(b) << 16);
}

// ---------------- CSR build ----------------
__global__ __launch_bounds__(256) void k_zero(int* __restrict__ p, int n) {
  int i = blockIdx.x * blockDim.x + threadIdx.x;
  if (i < n) p[i] = 0;
}

__global__ __launch_bounds__(256) void k_hist(const int* __restrict__ dst,
                                              int* __restrict__ deg, int e) {
  int i = blockIdx.x * blockDim.x + threadIdx.x;
  if (i < e) atomicAdd(&deg[dst[i]], 1);
}

// parallel scan pass 1: per-block exclusive scan of (deg[i]+1); block totals to bsum
__global__ __launch_bounds__(256) void k_scan1(const int* __restrict__ deg,
                                               int* __restrict__ off,
                                               int* __restrict__ bsum, int n) {
  __shared__ int wsum[4];
  int tid = threadIdx.x;
  int gid = blockIdx.x * 256 + tid;
  int lane = tid & 63, wid = tid >> 6;
  int v = (gid < n) ? (deg[gid] + 1) : 0;
  int x = v;
  #pragma unroll
  for (int d = 1; d < 64; d <<= 1) {
    int t = __shfl_up(x, d);
    if (lane >= d) x += t;
  }
  if (lane == 63) wsum[wid] = x;
  __syncthreads();
  int wpre = 0;
  for (int k = 0; k < wid; ++k) wpre += wsum[k];
  if (gid < n) off[gid] = wpre + x - v;
  if (tid == 0) {
    int t = 0;
    #pragma unroll
    for (int k = 0; k < 4; ++k) t += wsum[k];
    bsum[blockIdx.x] = t;
  }
}

// pass 2: single block scans block sums (nb <= 256) exclusive; total -> off[n]
__global__ __launch_bounds__(256) void k_scan2(int* __restrict__ bsum,
                                               int* __restrict__ off, int nb, int n) {
  __shared__ int wsum[4];
  int tid = threadIdx.x;
  int lane = tid & 63, wid = tid >> 6;
  int v = (tid < nb) ? bsum[tid] : 0;
  int x = v;
  #pragma unroll
  for (int d = 1; d < 64; d <<= 1) {
    int t = __shfl_up(x, d);
    if (lane >= d) x += t;
  }
  if (lane == 63) wsum[wid] = x;
  __syncthreads();
  int wpre = 0;
  for (int k = 0; k < wid; ++k) wpre += wsum[k];
  if (tid < nb) bsum[tid] = wpre + x - v;
  if (tid == 0) {
    int t = 0;
    #pragma unroll
    for (int k = 0; k < 4; ++k) t += wsum[k];
    off[n] = t;
  }
}

// pass 3: add block prefix
__global__ __launch_bounds__(256) void k_scan3(int* __restrict__ off,
                                               const int* __restrict__ bsum, int n) {
  int gid = blockIdx.x * 256 + threadIdx.x;
  if (gid < n) off[gid] += bsum[blockIdx.x];
}

__global__ __launch_bounds__(256) void k_initpos(const int* __restrict__ off,
                                                 int* __restrict__ pos,
                                                 int* __restrict__ csr, int n) {
  int i = blockIdx.x * blockDim.x + threadIdx.x;
  if (i < n) {
    int o = off[i];
    csr[o] = i;  // self-loop occupies first slot
    pos[i] = o + 1;
  }
}

__global__ __launch_bounds__(256) void k_fill(const int* __restrict__ src,
                                              const int* __restrict__ dst,
                                              int* __restrict__ pos,
                                              int* __restrict__ csr, int e) {
  int i = blockIdx.x * blockDim.x + threadIdx.x;
  if (i < e) {
    int d = dst[i];
    int p = atomicAdd(&pos[d], 1);
    csr[p] = src[i];
  }
}

// ---------------- layer 0: emb @ W (3x16 @ 16x128) tables ----------------
// tlb: packed bf16 pairs (3 x 64 uints); trf: f32 (3 x 128)
__global__ __launch_bounds__(256) void k_embw(const float* __restrict__ emb,
                                              const float* __restrict__ wl,
                                              const float* __restrict__ wr,
                                              unsigned* __restrict__ tlb,
                                              float* __restrict__ trf) {
  int tid = threadIdx.x;
  if (tid >= 192) return;
  int row = tid >> 6, cp = tid & 63, c0 = cp * 2;
  float al0 = 0.f, al1 = 0.f, ar0 = 0.f, ar1 = 0.f;
  #pragma unroll
  for (int k = 0; k < 16; ++k) {
    float ev = emb[row * 16 + k];
    al0 += ev * wl[k * 128 + c0];
    al1 += ev * wl[k * 128 + c0 + 1];
    ar0 += ev * wr[k * 128 + c0];
    ar1 += ev * wr[k * 128 + c0 + 1];
  }
  tlb[row * 64 + cp] = packbf(al0, al1);
  *(float2*)(trf + row * 128 + c0) = make_float2(ar0, ar1);
}

// ---------------- layer-0 aggregation via neighbor-type histogram ----------------
__global__ __launch_bounds__(256)
void k_agg0(const int* __restrict__ off, const int* __restrict__ csr,
            const int* __restrict__ types,
            const unsigned* __restrict__ tlb, const float* __restrict__ trf,
            const float* __restrict__ att, const float* __restrict__ bias,
            const float* __restrict__ lng, const float* __restrict__ lnb,
            unsigned* __restrict__ yout, int n) {
  int v = (blockIdx.x * blockDim.x + threadIdx.x) >> 6;
  int lane = threadIdx.x & 63;
  if (v >= n) return;
  v = __builtin_amdgcn_readfirstlane(v);
  int beg = off[v], end = off[v + 1];
  int c0 = 0, c1 = 0, c2 = 0;
  for (int base = beg; base < end; base += 64) {
    int e = base + lane;
    bool act = e < end;
    int u = act ? csr[e] : 0;
    int ty = act ? types[u] : 3;
    c0 += __popcll(__ballot(ty == 0));
    c1 += __popcll(__ballot(ty == 1));
    c2 += __popcll(__ballot(ty == 2));
  }
  float cnt[3] = {(float)c0, (float)c1, (float)c2};
  int f0 = lane * 2;
  int tyv = types[v];
  float2 xrv = *(const float2*)(trf + tyv * 128 + f0);
  float a0 = att[f0], a1 = att[f0 + 1];
  float s = 0.f, O0 = 0.f, O1 = 0.f;
  #pragma unroll
  for (int ty = 0; ty < 3; ++ty) {
    unsigned p = tlb[ty * 64 + lane];
    float x0 = bf2f_lo(p), x1 = bf2f_hi(p);
    float t0 = x0 + xrv.x; t0 = t0 > 0.f ? t0 : 0.2f * t0;
    float t1 = x1 + xrv.y; t1 = t1 > 0.f ? t1 : 0.2f * t1;
    float c = t0 * a0 + t1 * a1;
    c += __shfl_xor(c, 1);
    c += __shfl_xor(c, 2);
    c += __shfl_xor(c, 4);
    c += __shfl_xor(c, 8);
    float w = cnt[ty] * __expf(c);
    s += w;
    O0 = fmaf(w, x0, O0);
    O1 = fmaf(w, x1, O1);
  }
  float inv = 1.f / s;
  float o0 = O0 * inv + bias[f0];
  float o1 = O1 * inv + bias[f0 + 1];
  float sum = o0 + o1, sq = o0 * o0 + o1 * o1;
  #pragma unroll
  for (int d2 = 1; d2 < 64; d2 <<= 1) {
    sum += __shfl_xor(sum, d2);
    sq += __shfl_xor(sq, d2);
  }
  float mu = sum * (1.f / 128.f);
  float var = sq * (1.f / 128.f) - mu * mu;
  float rstd = rsqrtf(var + 1e-5f);
  float y0 = fmaxf((o0 - mu) * rstd * lng[f0] + lnb[f0], 0.f);
  float y1 = fmaxf((o1 - mu) * rstd * lng[f0 + 1] + lnb[f0 + 1], 0.f);
  yout[(size_t)v * 64 + lane] = packbf(y0, y1);
}

// ---------------- pack [Wl|Wr] (f32 128x128 each) into MFMA B-fragment bf16 ----------
// bp[((t*16+ct)*64+lane)*8+j] = W[k=t*32+(lane>>4)*8+j][c=ct*16+(lane&15)], c<128->Wl
__global__ __launch_bounds__(256) void k_pack(const float* __restrict__ wl,
                                              const float* __restrict__ wr,
                                              unsigned short* __restrict__ bp) {
  int idx = blockIdx.x * 256 + threadIdx.x;
  if (idx >= 32768) return;
  int j = idx & 7, lane = (idx >> 3) & 63, ct = (idx >> 9) & 15, t = idx >> 13;
  int k = t * 32 + (lane >> 4) * 8 + j;
  int c = ct * 16 + (lane & 15);
  float v = (c < 128) ? wl[k * 128 + c] : wr[k * 128 + (c - 128)];
  bp[idx] = f2bf(v);
}

// ---------------- GEMM (MFMA): x(Nx128 bf16 packed) @ [Wl|Wr] -> xl, xr (bf16 packed) ----
// One wave per 16-row strip; 64x mfma_f32_16x16x32_bf16; no LDS.
// A-frag: A[m=lane&15][k=quad*8+j]; C/D: col=lane&15, row=quad*4+reg (guide-verified).
__global__ __launch_bounds__(256)
void k_gemm(const unsigned* __restrict__ x, const unsigned short* __restrict__ bp,
            unsigned* __restrict__ xlo, unsigned* __restrict__ xro, int nstrips, int n) {
  int wave = (blockIdx.x * 256 + threadIdx.x) >> 6;
  int lane = threadIdx.x & 63;
  if (wave >= nstrips) return;
  int r0 = wave * 16;
  int row = r0 + (lane & 15);
  if (row >= n) row = n - 1;
  int quad = lane >> 4;
  const uint4* ap = (const uint4*)(x + (size_t)row * 64);
  bfrag8 a[4];
  #pragma unroll
  for (int t = 0; t < 4; ++t) a[t] = *(const bfrag8*)(ap + t * 4 + quad);
  unsigned short* xloS = (unsigned short*)xlo;
  unsigned short* xroS = (unsigned short*)xro;
  int rbase = r0 + quad * 4;
  #pragma unroll
  for (int ct = 0; ct < 16; ++ct) {
    facc4 acc = {0.f, 0.f, 0.f, 0.f};
    #pragma unroll
    for (int t = 0; t < 4; ++t) {
      bfrag8 b = *(const bfrag8*)(bp + (size_t)(((t * 16 + ct) * 64 + lane) * 8));
      acc = __builtin_amdgcn_mfma_f32_16x16x32_bf16(a[t], b, acc, 0, 0, 0);
    }
    int col = (ct & 7) * 16 + (lane & 15);
    unsigned short* dstp = (ct < 8) ? xloS : xroS;
    #pragma unroll
    for (int i = 0; i < 4; ++i) {
      int r = rbase + i;
      if (r < n) dstp[(size_t)r * 128 + col] = f2bf(acc[i]);
    }
  }
}

// ---------------- fused aggregate + bias + residual + LN + ReLU ----------------
// one wave per dst node; lane owns features 2*lane, 2*lane+1; all activations
// packed bf16. No-max softmax; unroll-2, prefetch-4 (proven round-8/10 structure).
__global__ __launch_bounds__(256)
void k_agg(const int* __restrict__ off, const int* __restrict__ csr,
           const unsigned* __restrict__ xl, const unsigned* __restrict__ xr,
           const float* __restrict__ att, const float* __restrict__ bias,
           const unsigned* __restrict__ xres,
           const float* __restrict__ lng, const float* __restrict__ lnb,
           unsigned* __restrict__ ybf, float* __restrict__ yf32, int n, int wide) {
  int v = (blockIdx.x * blockDim.x + threadIdx.x) >> 6;
  int lane = threadIdx.x & 63;
  if (v >= n) return;
  v = __builtin_amdgcn_readfirstlane(v);
  int f0 = lane * 2;
  float a0 = att[f0], a1 = att[f0 + 1];
  unsigned rv = xr[(size_t)v * 64 + lane];
  float r0 = bf2f_lo(rv), r1 = bf2f_hi(rv);
  int beg = off[v], end = off[v + 1];
  int last = end - 1;
  const unsigned* xlp = xl + lane;  // row r at xlp[r*64]
  int iA = csr[beg];
  int iB = csr[min(beg + 1, last)];
  int iC = csr[min(beg + 2, last)];
  int iD = csr[min(beg + 3, last)];
  unsigned pA = xlp[(size_t)iA * 64];
  unsigned pB = xlp[(size_t)iB * 64];
  unsigned pC = xlp[(size_t)iC * 64];
  unsigned pD = xlp[(size_t)iD * 64];
  float sa = 0.f, Oa0 = 0.f, Oa1 = 0.f;
  float sb = 0.f, Ob0 = 0.f, Ob1 = 0.f;
  for (int e = beg; e < end; e += 2) {
    int i4 = csr[min(e + 4, last)];
    int i5 = csr[min(e + 5, last)];
    unsigned p4 = xlp[(size_t)i4 * 64];
    unsigned p5 = xlp[(size_t)i5 * 64];
    float x0a = bf2f_lo(pA), x1a = bf2f_hi(pA);
    float x0b = bf2f_lo(pB), x1b = bf2f_hi(pB);
    float t0a = x0a + r0; t0a = t0a > 0.f ? t0a : 0.2f * t0a;
    float t1a = x1a + r1; t1a = t1a > 0.f ? t1a : 0.2f * t1a;
    float t0b = x0b + r0; t0b = t0b > 0.f ? t0b : 0.2f * t0b;
    float t1b = x1b + r1; t1b = t1b > 0.f ? t1b : 0.2f * t1b;
    float ca = t0a * a0 + t1a * a1;
    float cb = t0b * a0 + t1b * a1;
    ca += __shfl_xor(ca, 1); cb += __shfl_xor(cb, 1);
    ca += __shfl_xor(ca, 2); cb += __shfl_xor(cb, 2);
    ca += __shfl_xor(ca, 4); cb += __shfl_xor(cb, 4);
    ca += __shfl_xor(ca, 8); cb += __shfl_xor(cb, 8);
    if (wide) {
      ca += __shfl_xor(ca, 16); cb += __shfl_xor(cb, 16);
      ca += __shfl_xor(ca, 32); cb += __shfl_xor(cb, 32);
    }
    float wa = __expf(ca);
    float wb = (e + 1 < end) ? __expf(cb) : 0.f;
    sa += wa; Oa0 = fmaf(wa, x0a, Oa0); Oa1 = fmaf(wa, x1a, Oa1);
    sb += wb; Ob0 = fmaf(wb, x0b, Ob0); Ob1 = fmaf(wb, x1b, Ob1);
    pA = pC; pB = pD; pC = p4; pD = p5;
  }
  float s = sa + sb;
  float O0 = Oa0 + Ob0, O1 = Oa1 + Ob1;
  float inv = 1.f / s;
  float o0 = O0 * inv + bias[f0];
  float o1 = O1 * inv + bias[f0 + 1];
  if (xres) {
    unsigned rs = xres[(size_t)v * 64 + lane];
    o0 += bf2f_lo(rs);
    o1 += bf2f_hi(rs);
  }
  float sum = o0 + o1, sq = o0 * o0 + o1 * o1;
  #pragma unroll
  for (int d2 = 1; d2 < 64; d2 <<= 1) {
    sum += __shfl_xor(sum, d2);
    sq += __shfl_xor(sq, d2);
  }
  float mu = sum * (1.f / 128.f);
  float var = sq * (1.f / 128.f) - mu * mu;
  float rstd = rsqrtf(var + 1e-5f);
  float y0 = fmaxf((o0 - mu) * rstd * lng[f0] + lnb[f0], 0.f);
  float y1 = fmaxf((o1 - mu) * rstd * lng[f0 + 1] + lnb[f0 + 1], 0.f);
  if (yf32) {
    *(float2*)(yf32 + (size_t)v * 128 + f0) = make_float2(y0, y1);
  } else {
    ybf[(size_t)v * 64 + lane] = packbf(y0, y1);
  }
}

// ---------------- launch ----------------
extern "C" void kernel_launch(void* const* d_in, const int* in_sizes, int n_in,
                              void* d_out, int out_size, void* d_ws, size_t ws_size,
                              hipStream_t stream) {
  (void)n_in; (void)out_size; (void)ws_size;
  const int* node_types = (const int*)d_in[0];
  const int* edge_index = (const int*)d_in[1];
  const float* emb = (const float*)d_in[2];
  const float* Wl0 = (const float*)d_in[3];
  const float* Wr0 = (const float*)d_in[4];
  const float* att0 = (const float*)d_in[5];
  const float* b0 = (const float*)d_in[6];
  const float* Wl1 = (const float*)d_in[7];
  const float* Wr1 = (const float*)d_in[8];
  const float* att1 = (const float*)d_in[9];
  const float* b1 = (const float*)d_in[10];
  const float* Wl2 = (const float*)d_in[11];
  const float* Wr2 = (const float*)d_in[12];
  const float* att2 = (const float*)d_in[13];
  const float* b2 = (const float*)d_in[14];
  const float* Wl3 = (const float*)d_in[15];
  const float* Wr3 = (const float*)d_in[16];
  const float* att3 = (const float*)d_in[17];
  const float* b3 = (const float*)d_in[18];
  const float* lng = (const float*)d_in[19];
  const float* lnb = (const float*)d_in[20];

  int n = in_sizes[0];
  int e = in_sizes[1] / 2;
  const int* srcp = edge_index;
  const int* dstp = edge_index + e;
  int nblocks = (n + 255) / 256;

  // workspace carve (256-byte aligned chunks)
  char* wsp = (char*)d_ws;
  size_t ofs = 0;
  int* deg = (int*)(wsp + ofs); ofs += (((size_t)n * 4) + 255) & ~(size_t)255;
  int* off = (int*)(wsp + ofs); ofs += (((size_t)(n + 1) * 4) + 255) & ~(size_t)255;
  int* csr = (int*)(wsp + ofs); ofs += (((size_t)(e + n) * 4) + 255) & ~(size_t)255;
  int* bsum = (int*)(wsp + ofs); ofs += (((size_t)nblocks * 4) + 255) & ~(size_t)255;
  unsigned* xlb = (unsigned*)(wsp + ofs); ofs += (((size_t)n * 64 * 4) + 255) & ~(size_t)255;
  unsigned* xrb = (unsigned*)(wsp + ofs); ofs += (((size_t)n * 64 * 4) + 255) & ~(size_t)255;
  unsigned* xcur = (unsigned*)(wsp + ofs); ofs += (((size_t)n * 64 * 4) + 255) & ~(size_t)255;
  unsigned short* bp = (unsigned short*)(wsp + ofs); ofs += 65536;
  unsigned* tlb = (unsigned*)(wsp + ofs); ofs += 1024;
  float* trf = (float*)(wsp + ofs); ofs += 2048;
  int* pos = deg;  // deg dead after scan; reuse as fill cursor

  // CSR build (graph identical across all 4 layers)
  k_zero<<<nblocks, 256, 0, stream>>>(deg, n);
  k_hist<<<(e + 255) / 256, 256, 0, stream>>>(dstp, deg, e);
  k_scan1<<<nblocks, 256, 0, stream>>>(deg, off, bsum, n);
  k_scan2<<<1, 256, 0, stream>>>(bsum, off, nblocks, n);
  k_scan3<<<nblocks, 256, 0, stream>>>(off, bsum, n);
  k_initpos<<<nblocks, 256, 0, stream>>>(off, pos, csr, n);
  k_fill<<<(e + 255) / 256, 256, 0, stream>>>(srcp, dstp, pos, csr, e);

  int aggBlocks = (n * 64 + 255) / 256;  // one wave per node

  // layer 0: type-table aggregation (ballot histogram; writes bf16 xcur)
  k_embw<<<1, 256, 0, stream>>>(emb, Wl0, Wr0, tlb, trf);
  k_agg0<<<aggBlocks, 256, 0, stream>>>(off, csr, node_types, tlb, trf,
                                        att0, b0, lng, lnb, xcur, n);

  int nstrips = (n + 15) / 16;
  int gemmBlocks = (nstrips + 3) / 4;

  // layer 1
  k_pack<<<128, 256, 0, stream>>>(Wl1, Wr1, bp);
  k_gemm<<<gemmBlocks, 256, 0, stream>>>(xcur, bp, xlb, xrb, nstrips, n);
  k_agg<<<aggBlocks, 256, 0, stream>>>(off, csr, xlb, xrb, att1, b1, xcur,
                                       lng + 128, lnb + 128, xcur, (float*)0, n, 0);
  // layer 2
  k_pack<<<128, 256, 0, stream>>>(Wl2, Wr2, bp);
  k_gemm<<<gemmBlocks, 256, 0, stream>>>(xcur, bp, xlb, xrb, nstrips, n);
  k_agg<<<aggBlocks, 256, 0, stream>>>(off, csr, xlb, xrb, att2, b2, xcur,
                                       lng + 256, lnb + 256, xcur, (float*)0, n, 0);
  // layer 3 (single head, wide reduce; f32 output to d_out)
  k_pack<<<128, 256, 0, stream>>>(Wl3, Wr3, bp);
  k_gemm<<<gemmBlocks, 256, 0, stream>>>(xcur, bp, xlb, xrb, nstrips, n);
  k_agg<<<aggBlocks, 256, 0, stream>>>(off, csr, xlb, xrb, att3, b3, xcur,
                                       lng + 384, lnb + 384, (unsigned*)0, (float*)d_out, n, 1);
}

// Round 14
// 445.499 us; speedup vs baseline: 1.3666x; 1.0017x over previous
//
#include <hip/hip_runtime.h>

// Harness-provided kernel symbol kept (not required to do work).
__global__ void GraphEncoder_20555713479231_kernel() {}

using hfrag8 = __attribute__((ext_vector_type(8))) _Float16;  // 8 f16 (4 VGPRs)
using facc4  = __attribute__((ext_vector_type(4))) float;     // 4 fp32 acc
using h2     = __attribute__((ext_vector_type(2))) _Float16;  // packed f16 pair

__device__ __forceinline__ unsigned short f2h_bits(float f) {
  union { _Float16 h; unsigned short u; } c;
  c.h = (_Float16)f;
  return c.u;
}
__device__ __forceinline__ unsigned packh(float a, float b) {
  return (unsigned)f2h_bits(a) | ((unsigned)f2h_bits(b) << 16);
}
__device__ __forceinline__ h2 u2h(unsigned u) {
  union { unsigned u; h2 h; } c;
  c.u = u;
  return c.h;
}
__device__ __forceinline__ float h2f_lo(unsigned u) { return (float)u2h(u).x; }
__device__ __forceinline__ float h2f_hi(unsigned u) { return (float)u2h(u).y; }

// ---------------- CSR build ----------------
__global__ __launch_bounds__(256) void k_hist(const int* __restrict__ dst,
                                              int* __restrict__ deg, int e) {
  int i = blockIdx.x * blockDim.x + threadIdx.x;
  if (i < e) atomicAdd(&deg[dst[i]], 1);
}

// parallel scan pass 1: per-block exclusive scan of (deg[i]+1); block totals to bsum
__global__ __launch_bounds__(256) void k_scan1(const int* __restrict__ deg,
                                               int* __restrict__ off,
                                               int* __restrict__ bsum, int n) {
  __shared__ int wsum[4];
  int tid = threadIdx.x;
  int gid = blockIdx.x * 256 + tid;
  int lane = tid & 63, wid = tid >> 6;
  int v = (gid < n) ? (deg[gid] + 1) : 0;
  int x = v;
  #pragma unroll
  for (int d = 1; d < 64; d <<= 1) {
    int t = __shfl_up(x, d);
    if (lane >= d) x += t;
  }
  if (lane == 63) wsum[wid] = x;
  __syncthreads();
  int wpre = 0;
  for (int k = 0; k < wid; ++k) wpre += wsum[k];
  if (gid < n) off[gid] = wpre + x - v;
  if (tid == 0) {
    int t = 0;
    #pragma unroll
    for (int k = 0; k < 4; ++k) t += wsum[k];
    bsum[blockIdx.x] = t;
  }
}

// pass 2: single block scans block sums (nb <= 256) exclusive; total -> off[n]
__global__ __launch_bounds__(256) void k_scan2(int* __restrict__ bsum,
                                               int* __restrict__ off, int nb, int n) {
  __shared__ int wsum[4];
  int tid = threadIdx.x;
  int lane = tid & 63, wid = tid >> 6;
  int v = (tid < nb) ? bsum[tid] : 0;
  int x = v;
  #pragma unroll
  for (int d = 1; d < 64; d <<= 1) {
    int t = __shfl_up(x, d);
    if (lane >= d) x += t;
  }
  if (lane == 63) wsum[wid] = x;
  __syncthreads();
  int wpre = 0;
  for (int k = 0; k < wid; ++k) wpre += wsum[k];
  if (tid < nb) bsum[tid] = wpre + x - v;
  if (tid == 0) {
    int t = 0;
    #pragma unroll
    for (int k = 0; k < 4; ++k) t += wsum[k];
    off[n] = t;
  }
}

// pass 3: add block prefix; also init self-loop slot and fill cursor (fused initpos)
__global__ __launch_bounds__(256) void k_scan3(int* __restrict__ off,
                                               const int* __restrict__ bsum,
                                               int* __restrict__ pos,
                                               int* __restrict__ csr, int n) {
  int gid = blockIdx.x * 256 + threadIdx.x;
  if (gid < n) {
    int o = off[gid] + bsum[blockIdx.x];
    off[gid] = o;
    csr[o] = gid;  // self-loop occupies first slot
    pos[gid] = o + 1;
  }
}

__global__ __launch_bounds__(256) void k_fill(const int* __restrict__ src,
                                              const int* __restrict__ dst,
                                              int* __restrict__ pos,
                                              int* __restrict__ csr, int e) {
  int i = blockIdx.x * blockDim.x + threadIdx.x;
  if (i < e) {
    int d = dst[i];
    int p = atomicAdd(&pos[d], 1);
    csr[p] = src[i];
  }
}

// ---------------- layer 0: emb @ W (3x16 @ 16x128) tables ----------------
// tlb: packed f16 pairs (3 x 64 uints); trf: f32 (3 x 128)
__global__ __launch_bounds__(256) void k_embw(const float* __restrict__ emb,
                                              const float* __restrict__ wl,
                                              const float* __restrict__ wr,
                                              unsigned* __restrict__ tlb,
                                              float* __restrict__ trf) {
  int tid = threadIdx.x;
  if (tid >= 192) return;
  int row = tid >> 6, cp = tid & 63, c0 = cp * 2;
  float al0 = 0.f, al1 = 0.f, ar0 = 0.f, ar1 = 0.f;
  #pragma unroll
  for (int k = 0; k < 16; ++k) {
    float ev = emb[row * 16 + k];
    al0 += ev * wl[k * 128 + c0];
    al1 += ev * wl[k * 128 + c0 + 1];
    ar0 += ev * wr[k * 128 + c0];
    ar1 += ev * wr[k * 128 + c0 + 1];
  }
  tlb[row * 64 + cp] = packh(al0, al1);
  *(float2*)(trf + row * 128 + c0) = make_float2(ar0, ar1);
}

// ---------------- layer-0 aggregation via neighbor-type histogram ----------------
__global__ __launch_bounds__(256)
void k_agg0(const int* __restrict__ off, const int* __restrict__ csr,
            const int* __restrict__ types,
            const unsigned* __restrict__ tlb, const float* __restrict__ trf,
            const float* __restrict__ att, const float* __restrict__ bias,
            const float* __restrict__ lng, const float* __restrict__ lnb,
            unsigned* __restrict__ yout, int n) {
  int v = (blockIdx.x * blockDim.x + threadIdx.x) >> 6;
  int lane = threadIdx.x & 63;
  if (v >= n) return;
  v = __builtin_amdgcn_readfirstlane(v);
  int beg = off[v], end = off[v + 1];
  int c0 = 0, c1 = 0, c2 = 0;
  for (int base = beg; base < end; base += 64) {
    int e = base + lane;
    bool act = e < end;
    int u = act ? csr[e] : 0;
    int ty = act ? types[u] : 3;
    c0 += __popcll(__ballot(ty == 0));
    c1 += __popcll(__ballot(ty == 1));
    c2 += __popcll(__ballot(ty == 2));
  }
  float cnt[3] = {(float)c0, (float)c1, (float)c2};
  int f0 = lane * 2;
  int tyv = types[v];
  float2 xrv = *(const float2*)(trf + tyv * 128 + f0);
  float a0 = att[f0], a1 = att[f0 + 1];
  float s = 0.f, O0 = 0.f, O1 = 0.f;
  #pragma unroll
  for (int ty = 0; ty < 3; ++ty) {
    unsigned p = tlb[ty * 64 + lane];
    float x0 = h2f_lo(p), x1 = h2f_hi(p);
    float t0 = x0 + xrv.x; t0 = t0 > 0.f ? t0 : 0.2f * t0;
    float t1 = x1 + xrv.y; t1 = t1 > 0.f ? t1 : 0.2f * t1;
    float c = t0 * a0 + t1 * a1;
    c += __shfl_xor(c, 1);
    c += __shfl_xor(c, 2);
    c += __shfl_xor(c, 4);
    c += __shfl_xor(c, 8);
    float w = cnt[ty] * __expf(c);
    s += w;
    O0 = fmaf(w, x0, O0);
    O1 = fmaf(w, x1, O1);
  }
  float inv = 1.f / s;
  float o0 = O0 * inv + bias[f0];
  float o1 = O1 * inv + bias[f0 + 1];
  float sum = o0 + o1, sq = o0 * o0 + o1 * o1;
  #pragma unroll
  for (int d2 = 1; d2 < 64; d2 <<= 1) {
    sum += __shfl_xor(sum, d2);
    sq += __shfl_xor(sq, d2);
  }
  float mu = sum * (1.f / 128.f);
  float var = sq * (1.f / 128.f) - mu * mu;
  float rstd = rsqrtf(var + 1e-5f);
  float y0 = fmaxf((o0 - mu) * rstd * lng[f0] + lnb[f0], 0.f);
  float y1 = fmaxf((o1 - mu) * rstd * lng[f0 + 1] + lnb[f0 + 1], 0.f);
  yout[(size_t)v * 64 + lane] = packh(y0, y1);
}

// ---------------- pack [Wl|Wr] (f32 128x128 each) into MFMA B-fragment f16 ----------
// bp[((t*16+ct)*64+lane)*8+j] = W[k=t*32+(lane>>4)*8+j][c=ct*16+(lane&15)], c<128->Wl
__global__ __launch_bounds__(256) void k_pack(const float* __restrict__ wl,
                                              const float* __restrict__ wr,
                                              unsigned short* __restrict__ bp) {
  int idx = blockIdx.x * 256 + threadIdx.x;
  if (idx >= 32768) return;
  int j = idx & 7, lane = (idx >> 3) & 63, ct = (idx >> 9) & 15, t = idx >> 13;
  int k = t * 32 + (lane >> 4) * 8 + j;
  int c = ct * 16 + (lane & 15);
  float v = (c < 128) ? wl[k * 128 + c] : wr[k * 128 + (c - 128)];
  bp[idx] = f2h_bits(v);
}

// ---------------- GEMM (MFMA f16): x(Nx128 f16 packed) @ [Wl|Wr] -> xl, xr (f16 packed) ----
// One wave per 16-row strip; 64x mfma_f32_16x16x32_f16; no LDS.
// A-frag: A[m=lane&15][k=quad*8+j]; C/D: col=lane&15, row=quad*4+reg (guide-verified).
__global__ __launch_bounds__(256)
void k_gemm(const unsigned* __restrict__ x, const unsigned short* __restrict__ bp,
            unsigned* __restrict__ xlo, unsigned* __restrict__ xro, int nstrips, int n) {
  int wave = (blockIdx.x * 256 + threadIdx.x) >> 6;
  int lane = threadIdx.x & 63;
  if (wave >= nstrips) return;
  int r0 = wave * 16;
  int row = r0 + (lane & 15);
  if (row >= n) row = n - 1;
  int quad = lane >> 4;
  const unsigned* ap = x + (size_t)row * 64;
  hfrag8 a[4];
  #pragma unroll
  for (int t = 0; t < 4; ++t) a[t] = *(const hfrag8*)(ap + t * 16 + quad * 4);
  unsigned short* xloS = (unsigned short*)xlo;
  unsigned short* xroS = (unsigned short*)xro;
  int rbase = r0 + quad * 4;
  #pragma unroll
  for (int ct = 0; ct < 16; ++ct) {
    facc4 acc = {0.f, 0.f, 0.f, 0.f};
    #pragma unroll
    for (int t = 0; t < 4; ++t) {
      hfrag8 b = *(const hfrag8*)(bp + (size_t)(((t * 16 + ct) * 64 + lane) * 8));
      acc = __builtin_amdgcn_mfma_f32_16x16x32_f16(a[t], b, acc, 0, 0, 0);
    }
    int col = (ct & 7) * 16 + (lane & 15);
    unsigned short* dstp = (ct < 8) ? xloS : xroS;
    #pragma unroll
    for (int i = 0; i < 4; ++i) {
      int r = rbase + i;
      if (r < n) dstp[(size_t)r * 128 + col] = f2h_bits(acc[i]);
    }
  }
}

// ---------------- fused aggregate + bias + residual + LN + ReLU (f16 packed math) ----
// one wave per dst node; lane owns features 2*lane, 2*lane+1; activations f16 pairs.
// lrelu = max(t, 0.2t) via v_pk_max_f16; no-max softmax; unroll-2, prefetch-4.
__global__ __launch_bounds__(256)
void k_agg(const int* __restrict__ off, const int* __restrict__ csr,
           const unsigned* __restrict__ xl, const unsigned* __restrict__ xr,
           const float* __restrict__ att, const float* __restrict__ bias,
           const unsigned* __restrict__ xres,
           const float* __restrict__ lng, const float* __restrict__ lnb,
           unsigned* __restrict__ ybf, float* __restrict__ yf32, int n, int wide) {
  int v = (blockIdx.x * blockDim.x + threadIdx.x) >> 6;
  int lane = threadIdx.x & 63;
  if (v >= n) return;
  v = __builtin_amdgcn_readfirstlane(v);
  int f0 = lane * 2;
  h2 a2;
  a2.x = (_Float16)att[f0];
  a2.y = (_Float16)att[f0 + 1];
  h2 r2 = u2h(xr[(size_t)v * 64 + lane]);
  h2 k02 = {(_Float16)0.2f, (_Float16)0.2f};
  int beg = off[v], end = off[v + 1];
  int last = end - 1;
  const unsigned* xlp = xl + lane;  // row r at xlp[r*64]
  int iA = csr[beg];
  int iB = csr[min(beg + 1, last)];
  int iC = csr[min(beg + 2, last)];
  int iD = csr[min(beg + 3, last)];
  unsigned pA = xlp[(size_t)iA * 64];
  unsigned pB = xlp[(size_t)iB * 64];
  unsigned pC = xlp[(size_t)iC * 64];
  unsigned pD = xlp[(size_t)iD * 64];
  float sa = 0.f, Oa0 = 0.f, Oa1 = 0.f;
  float sb = 0.f, Ob0 = 0.f, Ob1 = 0.f;
  for (int e = beg; e < end; e += 2) {
    int i4 = csr[min(e + 4, last)];
    int i5 = csr[min(e + 5, last)];
    unsigned p4 = xlp[(size_t)i4 * 64];
    unsigned p5 = xlp[(size_t)i5 * 64];
    h2 xa = u2h(pA), xb = u2h(pB);
    h2 ta = xa + r2;
    h2 tb = xb + r2;
    h2 la = __builtin_elementwise_max(ta, ta * k02);  // pk leaky relu
    h2 lb = __builtin_elementwise_max(tb, tb * k02);
    h2 da = la * a2;
    h2 db = lb * a2;
    float ca = (float)da.x + (float)da.y;
    float cb = (float)db.x + (float)db.y;
    ca += __shfl_xor(ca, 1); cb += __shfl_xor(cb, 1);
    ca += __shfl_xor(ca, 2); cb += __shfl_xor(cb, 2);
    ca += __shfl_xor(ca, 4); cb += __shfl_xor(cb, 4);
    ca += __shfl_xor(ca, 8); cb += __shfl_xor(cb, 8);
    if (wide) {
      ca += __shfl_xor(ca, 16); cb += __shfl_xor(cb, 16);
      ca += __shfl_xor(ca, 32); cb += __shfl_xor(cb, 32);
    }
    float wa = __expf(ca);
    float wb = (e + 1 < end) ? __expf(cb) : 0.f;
    sa += wa; Oa0 = fmaf(wa, (float)xa.x, Oa0); Oa1 = fmaf(wa, (float)xa.y, Oa1);
    sb += wb; Ob0 = fmaf(wb, (float)xb.x, Ob0); Ob1 = fmaf(wb, (float)xb.y, Ob1);
    pA = pC; pB = pD; pC = p4; pD = p5;
  }
  float s = sa + sb;
  float O0 = Oa0 + Ob0, O1 = Oa1 + Ob1;
  float inv = 1.f / s;
  float o0 = O0 * inv + bias[f0];
  float o1 = O1 * inv + bias[f0 + 1];
  if (xres) {
    unsigned rs = xres[(size_t)v * 64 + lane];
    o0 += h2f_lo(rs);
    o1 += h2f_hi(rs);
  }
  float sum = o0 + o1, sq = o0 * o0 + o1 * o1;
  #pragma unroll
  for (int d2 = 1; d2 < 64; d2 <<= 1) {
    sum += __shfl_xor(sum, d2);
    sq += __shfl_xor(sq, d2);
  }
  float mu = sum * (1.f / 128.f);
  float var = sq * (1.f / 128.f) - mu * mu;
  float rstd = rsqrtf(var + 1e-5f);
  float y0 = fmaxf((o0 - mu) * rstd * lng[f0] + lnb[f0], 0.f);
  float y1 = fmaxf((o1 - mu) * rstd * lng[f0 + 1] + lnb[f0 + 1], 0.f);
  if (yf32) {
    *(float2*)(yf32 + (size_t)v * 128 + f0) = make_float2(y0, y1);
  } else {
    ybf[(size_t)v * 64 + lane] = packh(y0, y1);
  }
}

// ---------------- launch ----------------
extern "C" void kernel_launch(void* const* d_in, const int* in_sizes, int n_in,
                              void* d_out, int out_size, void* d_ws, size_t ws_size,
                              hipStream_t stream) {
  (void)n_in; (void)out_size; (void)ws_size;
  const int* node_types = (const int*)d_in[0];
  const int* edge_index = (const int*)d_in[1];
  const float* emb = (const float*)d_in[2];
  const float* Wl0 = (const float*)d_in[3];
  const float* Wr0 = (const float*)d_in[4];
  const float* att0 = (const float*)d_in[5];
  const float* b0 = (const float*)d_in[6];
  const float* Wl1 = (const float*)d_in[7];
  const float* Wr1 = (const float*)d_in[8];
  const float* att1 = (const float*)d_in[9];
  const float* b1 = (const float*)d_in[10];
  const float* Wl2 = (const float*)d_in[11];
  const float* Wr2 = (const float*)d_in[12];
  const float* att2 = (const float*)d_in[13];
  const float* b2 = (const float*)d_in[14];
  const float* Wl3 = (const float*)d_in[15];
  const float* Wr3 = (const float*)d_in[16];
  const float* att3 = (const float*)d_in[17];
  const float* b3 = (const float*)d_in[18];
  const float* lng = (const float*)d_in[19];
  const float* lnb = (const float*)d_in[20];

  int n = in_sizes[0];
  int e = in_sizes[1] / 2;
  const int* srcp = edge_index;
  const int* dstp = edge_index + e;
  int nblocks = (n + 255) / 256;

  // workspace carve (256-byte aligned chunks)
  char* wsp = (char*)d_ws;
  size_t ofs = 0;
  int* deg = (int*)(wsp + ofs); ofs += (((size_t)n * 4) + 255) & ~(size_t)255;
  int* off = (int*)(wsp + ofs); ofs += (((size_t)(n + 1) * 4) + 255) & ~(size_t)255;
  int* csr = (int*)(wsp + ofs); ofs += (((size_t)(e + n) * 4) + 255) & ~(size_t)255;
  int* bsum = (int*)(wsp + ofs); ofs += (((size_t)nblocks * 4) + 255) & ~(size_t)255;
  unsigned* xlb = (unsigned*)(wsp + ofs); ofs += (((size_t)n * 64 * 4) + 255) & ~(size_t)255;
  unsigned* xrb = (unsigned*)(wsp + ofs); ofs += (((size_t)n * 64 * 4) + 255) & ~(size_t)255;
  unsigned* xcur = (unsigned*)(wsp + ofs); ofs += (((size_t)n * 64 * 4) + 255) & ~(size_t)255;
  unsigned short* bp = (unsigned short*)(wsp + ofs); ofs += 65536;
  unsigned* tlb = (unsigned*)(wsp + ofs); ofs += 1024;
  float* trf = (float*)(wsp + ofs); ofs += 2048;
  int* pos = deg;  // deg dead after scan; reuse as fill cursor

  // CSR build (graph identical across all 4 layers)
  (void)hipMemsetAsync(deg, 0, (size_t)n * 4, stream);
  k_hist<<<(e + 255) / 256, 256, 0, stream>>>(dstp, deg, e);
  k_scan1<<<nblocks, 256, 0, stream>>>(deg, off, bsum, n);
  k_scan2<<<1, 256, 0, stream>>>(bsum, off, nblocks, n);
  k_scan3<<<nblocks, 256, 0, stream>>>(off, bsum, pos, csr, n);
  k_fill<<<(e + 255) / 256, 256, 0, stream>>>(srcp, dstp, pos, csr, e);

  int aggBlocks = (n * 64 + 255) / 256;  // one wave per node

  // layer 0: type-table aggregation (ballot histogram; writes f16 xcur)
  k_embw<<<1, 256, 0, stream>>>(emb, Wl0, Wr0, tlb, trf);
  k_agg0<<<aggBlocks, 256, 0, stream>>>(off, csr, node_types, tlb, trf,
                                        att0, b0, lng, lnb, xcur, n);

  int nstrips = (n + 15) / 16;
  int gemmBlocks = (nstrips + 3) / 4;

  // layer 1
  k_pack<<<128, 256, 0, stream>>>(Wl1, Wr1, bp);
  k_gemm<<<gemmBlocks, 256, 0, stream>>>(xcur, bp, xlb, xrb, nstrips, n);
  k_agg<<<aggBlocks, 256, 0, stream>>>(off, csr, xlb, xrb, att1, b1, xcur,
                                       lng + 128, lnb + 128, xcur, (float*)0, n, 0);
  // layer 2
  k_pack<<<128, 256, 0, stream>>>(Wl2, Wr2, bp);
  k_gemm<<<gemmBlocks, 256, 0, stream>>>(xcur, bp, xlb, xrb, nstrips, n);
  k_agg<<<aggBlocks, 256, 0, stream>>>(off, csr, xlb, xrb, att2, b2, xcur,
                                       lng + 256, lnb + 256, xcur, (float*)0, n, 0);
  // layer 3 (single head, wide reduce; f32 output to d_out)
  k_pack<<<128, 256, 0, stream>>>(Wl3, Wr3, bp);
  k_gemm<<<gemmBlocks, 256, 0, stream>>>(xcur, bp, xlb, xrb, nstrips, n);
  k_agg<<<aggBlocks, 256, 0, stream>>>(off, csr, xlb, xrb, att3, b3, xcur,
                                       lng + 384, lnb + 384, (unsigned*)0, (float*)d_out, n, 1);
}

// Round 15
// 413.988 us; speedup vs baseline: 1.4706x; 1.0761x over previous
//
#include <hip/hip_runtime.h>

// Harness-provided kernel symbol kept (not required to do work).
__global__ void GraphEncoder_20555713479231_kernel() {}

using hfrag8 = __attribute__((ext_vector_type(8))) _Float16;  // 8 f16 (4 VGPRs)
using facc4  = __attribute__((ext_vector_type(4))) float;     // 4 fp32 acc
using h2     = __attribute__((ext_vector_type(2))) _Float16;  // packed f16 pair

__device__ __forceinline__ unsigned short f2h_bits(float f) {
  union { _Float16 h; unsigned short u; } c;
  c.h = (_Float16)f;
  return c.u;
}
__device__ __forceinline__ unsigned packh(float a, float b) {
  return (unsigned)f2h_bits(a) | ((unsigned)f2h_bits(b) << 16);
}
__device__ __forceinline__ h2 u2h(unsigned u) {
  union { unsigned u; h2 h; } c;
  c.u = u;
  return c.h;
}
__device__ __forceinline__ unsigned h22u(h2 h) {
  union { h2 h; unsigned u; } c;
  c.h = h;
  return c.u;
}
__device__ __forceinline__ float h2f_lo(unsigned u) { return (float)u2h(u).x; }
__device__ __forceinline__ float h2f_hi(unsigned u) { return (float)u2h(u).y; }

// ---------------- CSR build ----------------
__global__ __launch_bounds__(256) void k_hist(const int* __restrict__ dst,
                                              int* __restrict__ deg, int e) {
  int i = blockIdx.x * blockDim.x + threadIdx.x;
  if (i < e) atomicAdd(&deg[dst[i]], 1);
}

// parallel scan pass 1: per-block exclusive scan of (deg[i]+1); block totals to bsum
__global__ __launch_bounds__(256) void k_scan1(const int* __restrict__ deg,
                                               int* __restrict__ off,
                                               int* __restrict__ bsum, int n) {
  __shared__ int wsum[4];
  int tid = threadIdx.x;
  int gid = blockIdx.x * 256 + tid;
  int lane = tid & 63, wid = tid >> 6;
  int v = (gid < n) ? (deg[gid] + 1) : 0;
  int x = v;
  #pragma unroll
  for (int d = 1; d < 64; d <<= 1) {
    int t = __shfl_up(x, d);
    if (lane >= d) x += t;
  }
  if (lane == 63) wsum[wid] = x;
  __syncthreads();
  int wpre = 0;
  for (int k = 0; k < wid; ++k) wpre += wsum[k];
  if (gid < n) off[gid] = wpre + x - v;
  if (tid == 0) {
    int t = 0;
    #pragma unroll
    for (int k = 0; k < 4; ++k) t += wsum[k];
    bsum[blockIdx.x] = t;
  }
}

// pass 2: single block scans block sums (nb <= 256) exclusive; total -> off[n]
__global__ __launch_bounds__(256) void k_scan2(int* __restrict__ bsum,
                                               int* __restrict__ off, int nb, int n) {
  __shared__ int wsum[4];
  int tid = threadIdx.x;
  int lane = tid & 63, wid = tid >> 6;
  int v = (tid < nb) ? bsum[tid] : 0;
  int x = v;
  #pragma unroll
  for (int d = 1; d < 64; d <<= 1) {
    int t = __shfl_up(x, d);
    if (lane >= d) x += t;
  }
  if (lane == 63) wsum[wid] = x;
  __syncthreads();
  int wpre = 0;
  for (int k = 0; k < wid; ++k) wpre += wsum[k];
  if (tid < nb) bsum[tid] = wpre + x - v;
  if (tid == 0) {
    int t = 0;
    #pragma unroll
    for (int k = 0; k < 4; ++k) t += wsum[k];
    off[n] = t;
  }
}

// pass 3: add block prefix; also init self-loop slot and fill cursor (fused initpos)
__global__ __launch_bounds__(256) void k_scan3(int* __restrict__ off,
                                               const int* __restrict__ bsum,
                                               int* __restrict__ pos,
                                               int* __restrict__ csr, int n) {
  int gid = blockIdx.x * 256 + threadIdx.x;
  if (gid < n) {
    int o = off[gid] + bsum[blockIdx.x];
    off[gid] = o;
    csr[o] = gid;  // self-loop occupies first slot
    pos[gid] = o + 1;
  }
}

__global__ __launch_bounds__(256) void k_fill(const int* __restrict__ src,
                                              const int* __restrict__ dst,
                                              int* __restrict__ pos,
                                              int* __restrict__ csr, int e) {
  int i = blockIdx.x * blockDim.x + threadIdx.x;
  if (i < e) {
    int d = dst[i];
    int p = atomicAdd(&pos[d], 1);
    csr[p] = src[i];
  }
}

// ---------------- pack weights (3 layers) + layer-0 tables, one dispatch ----------
// blocks 0..383: bp[layer][((t*16+ct)*64+lane)*8+j] =
//   W[k=t*32+(lane>>4)*8+j][c=ct*16+(lane&15)], c<128->Wl else Wr (f16)
// block 384: emb @ W0 tables -> tlb (f16 pairs), trf (f32)
__global__ __launch_bounds__(256)
void k_pack3(const float* __restrict__ wl1, const float* __restrict__ wr1,
             const float* __restrict__ wl2, const float* __restrict__ wr2,
             const float* __restrict__ wl3, const float* __restrict__ wr3,
             const float* __restrict__ emb,
             const float* __restrict__ wl0, const float* __restrict__ wr0,
             unsigned short* __restrict__ bp,
             unsigned* __restrict__ tlb, float* __restrict__ trf) {
  int b = blockIdx.x;
  if (b < 384) {
    int idx = b * 256 + threadIdx.x;  // 0..98303
    int layer = idx >> 15;
    int r = idx & 32767;
    int j = r & 7, lane = (r >> 3) & 63, ct = (r >> 9) & 15, t = r >> 13;
    int k = t * 32 + (lane >> 4) * 8 + j;
    int c = ct * 16 + (lane & 15);
    const float* wl = (layer == 0) ? wl1 : ((layer == 1) ? wl2 : wl3);
    const float* wr = (layer == 0) ? wr1 : ((layer == 1) ? wr2 : wr3);
    float v = (c < 128) ? wl[k * 128 + c] : wr[k * 128 + (c - 128)];
    bp[idx] = f2h_bits(v);
  } else {
    int tid = threadIdx.x;
    if (tid >= 192) return;
    int row = tid >> 6, cp = tid & 63, c0 = cp * 2;
    float al0 = 0.f, al1 = 0.f, ar0 = 0.f, ar1 = 0.f;
    #pragma unroll
    for (int k = 0; k < 16; ++k) {
      float ev = emb[row * 16 + k];
      al0 += ev * wl0[k * 128 + c0];
      al1 += ev * wl0[k * 128 + c0 + 1];
      ar0 += ev * wr0[k * 128 + c0];
      ar1 += ev * wr0[k * 128 + c0 + 1];
    }
    tlb[row * 64 + cp] = packh(al0, al1);
    *(float2*)(trf + row * 128 + c0) = make_float2(ar0, ar1);
  }
}

// ---------------- layer-0 aggregation via neighbor-type histogram ----------------
__global__ __launch_bounds__(256)
void k_agg0(const int* __restrict__ off, const int* __restrict__ csr,
            const int* __restrict__ types,
            const unsigned* __restrict__ tlb, const float* __restrict__ trf,
            const float* __restrict__ att, const float* __restrict__ bias,
            const float* __restrict__ lng, const float* __restrict__ lnb,
            unsigned* __restrict__ yout, int n) {
  int v = (blockIdx.x * blockDim.x + threadIdx.x) >> 6;
  int lane = threadIdx.x & 63;
  if (v >= n) return;
  v = __builtin_amdgcn_readfirstlane(v);
  int beg = off[v], end = off[v + 1];
  int c0 = 0, c1 = 0, c2 = 0;
  for (int base = beg; base < end; base += 64) {
    int e = base + lane;
    bool act = e < end;
    int u = act ? csr[e] : 0;
    int ty = act ? types[u] : 3;
    c0 += __popcll(__ballot(ty == 0));
    c1 += __popcll(__ballot(ty == 1));
    c2 += __popcll(__ballot(ty == 2));
  }
  float cnt[3] = {(float)c0, (float)c1, (float)c2};
  int f0 = lane * 2;
  int tyv = types[v];
  float2 xrv = *(const float2*)(trf + tyv * 128 + f0);
  float a0 = att[f0], a1 = att[f0 + 1];
  float s = 0.f, O0 = 0.f, O1 = 0.f;
  #pragma unroll
  for (int ty = 0; ty < 3; ++ty) {
    unsigned p = tlb[ty * 64 + lane];
    float x0 = h2f_lo(p), x1 = h2f_hi(p);
    float t0 = x0 + xrv.x; t0 = t0 > 0.f ? t0 : 0.2f * t0;
    float t1 = x1 + xrv.y; t1 = t1 > 0.f ? t1 : 0.2f * t1;
    float c = t0 * a0 + t1 * a1;
    c += __shfl_xor(c, 1);
    c += __shfl_xor(c, 2);
    c += __shfl_xor(c, 4);
    c += __shfl_xor(c, 8);
    float w = cnt[ty] * __expf(c);
    s += w;
    O0 = fmaf(w, x0, O0);
    O1 = fmaf(w, x1, O1);
  }
  float inv = 1.f / s;
  float o0 = O0 * inv + bias[f0];
  float o1 = O1 * inv + bias[f0 + 1];
  float sum = o0 + o1, sq = o0 * o0 + o1 * o1;
  #pragma unroll
  for (int d2 = 1; d2 < 64; d2 <<= 1) {
    sum += __shfl_xor(sum, d2);
    sq += __shfl_xor(sq, d2);
  }
  float mu = sum * (1.f / 128.f);
  float var = sq * (1.f / 128.f) - mu * mu;
  float rstd = rsqrtf(var + 1e-5f);
  float y0 = fmaxf((o0 - mu) * rstd * lng[f0] + lnb[f0], 0.f);
  float y1 = fmaxf((o1 - mu) * rstd * lng[f0 + 1] + lnb[f0 + 1], 0.f);
  yout[(size_t)v * 64 + lane] = packh(y0, y1);
}

// ---------------- GEMM (MFMA f16): x(Nx128 f16 packed) @ [Wl|Wr] -> xl, xr (f16 packed) ----
// One wave per 16-row strip; 64x mfma_f32_16x16x32_f16; no LDS.
// A-frag: A[m=lane&15][k=quad*8+j]; C/D: col=lane&15, row=quad*4+reg (guide-verified).
__global__ __launch_bounds__(256)
void k_gemm(const unsigned* __restrict__ x, const unsigned short* __restrict__ bp,
            unsigned* __restrict__ xlo, unsigned* __restrict__ xro, int nstrips, int n) {
  int wave = (blockIdx.x * 256 + threadIdx.x) >> 6;
  int lane = threadIdx.x & 63;
  if (wave >= nstrips) return;
  int r0 = wave * 16;
  int row = r0 + (lane & 15);
  if (row >= n) row = n - 1;
  int quad = lane >> 4;
  const unsigned* ap = x + (size_t)row * 64;
  hfrag8 a[4];
  #pragma unroll
  for (int t = 0; t < 4; ++t) a[t] = *(const hfrag8*)(ap + t * 16 + quad * 4);
  unsigned short* xloS = (unsigned short*)xlo;
  unsigned short* xroS = (unsigned short*)xro;
  int rbase = r0 + quad * 4;
  #pragma unroll
  for (int ct = 0; ct < 16; ++ct) {
    facc4 acc = {0.f, 0.f, 0.f, 0.f};
    #pragma unroll
    for (int t = 0; t < 4; ++t) {
      hfrag8 b = *(const hfrag8*)(bp + (size_t)(((t * 16 + ct) * 64 + lane) * 8));
      acc = __builtin_amdgcn_mfma_f32_16x16x32_f16(a[t], b, acc, 0, 0, 0);
    }
    int col = (ct & 7) * 16 + (lane & 15);
    unsigned short* dstp = (ct < 8) ? xloS : xroS;
    #pragma unroll
    for (int i = 0; i < 4; ++i) {
      int r = rbase + i;
      if (r < n) dstp[(size_t)r * 128 + col] = f2h_bits(acc[i]);
    }
  }
}

// ---------------- fused aggregate + bias + residual + LN + ReLU (f16 packed) ----------
// one wave per dst node; lane owns features 2*lane, 2*lane+1; activations f16 pairs.
// Both unrolled edges' logits ride one packed h2 through a single shuffle tree
// (v_pk_add_f16): 4 bpermutes per 2 edges instead of 8.
__global__ __launch_bounds__(256)
void k_agg(const int* __restrict__ off, const int* __restrict__ csr,
           const unsigned* __restrict__ xl, const unsigned* __restrict__ xr,
           const float* __restrict__ att, const float* __restrict__ bias,
           const unsigned* __restrict__ xres,
           const float* __restrict__ lng, const float* __restrict__ lnb,
           unsigned* __restrict__ ybf, float* __restrict__ yf32, int n, int wide) {
  int v = (blockIdx.x * blockDim.x + threadIdx.x) >> 6;
  int lane = threadIdx.x & 63;
  if (v >= n) return;
  v = __builtin_amdgcn_readfirstlane(v);
  int f0 = lane * 2;
  h2 a2;
  a2.x = (_Float16)att[f0];
  a2.y = (_Float16)att[f0 + 1];
  h2 r2 = u2h(xr[(size_t)v * 64 + lane]);
  h2 k02 = {(_Float16)0.2f, (_Float16)0.2f};
  int beg = off[v], end = off[v + 1];
  int last = end - 1;
  const unsigned* xlp = xl + lane;  // row r at xlp[r*64]
  int iA = csr[beg];
  int iB = csr[min(beg + 1, last)];
  int iC = csr[min(beg + 2, last)];
  int iD = csr[min(beg + 3, last)];
  unsigned pA = xlp[(size_t)iA * 64];
  unsigned pB = xlp[(size_t)iB * 64];
  unsigned pC = xlp[(size_t)iC * 64];
  unsigned pD = xlp[(size_t)iD * 64];
  float sa = 0.f, Oa0 = 0.f, Oa1 = 0.f;
  float sb = 0.f, Ob0 = 0.f, Ob1 = 0.f;
  for (int e = beg; e < end; e += 2) {
    int i4 = csr[min(e + 4, last)];
    int i5 = csr[min(e + 5, last)];
    unsigned p4 = xlp[(size_t)i4 * 64];
    unsigned p5 = xlp[(size_t)i5 * 64];
    h2 xa = u2h(pA), xb = u2h(pB);
    h2 ta = xa + r2;
    h2 tb = xb + r2;
    h2 la = __builtin_elementwise_max(ta, ta * k02);  // pk leaky relu
    h2 lb = __builtin_elementwise_max(tb, tb * k02);
    h2 da = la * a2;
    h2 db = lb * a2;
    h2 cp;
    cp.x = da.x + da.y;  // edge A partial logit
    cp.y = db.x + db.y;  // edge B partial logit
    unsigned cu = h22u(cp);
    cu = h22u(u2h(cu) + u2h((unsigned)__shfl_xor((int)cu, 1)));
    cu = h22u(u2h(cu) + u2h((unsigned)__shfl_xor((int)cu, 2)));
    cu = h22u(u2h(cu) + u2h((unsigned)__shfl_xor((int)cu, 4)));
    cu = h22u(u2h(cu) + u2h((unsigned)__shfl_xor((int)cu, 8)));
    if (wide) {
      cu = h22u(u2h(cu) + u2h((unsigned)__shfl_xor((int)cu, 16)));
      cu = h22u(u2h(cu) + u2h((unsigned)__shfl_xor((int)cu, 32)));
    }
    h2 cf = u2h(cu);
    float wa = __expf((float)cf.x);
    float wb = (e + 1 < end) ? __expf((float)cf.y) : 0.f;
    sa += wa; Oa0 = fmaf(wa, (float)xa.x, Oa0); Oa1 = fmaf(wa, (float)xa.y, Oa1);
    sb += wb; Ob0 = fmaf(wb, (float)xb.x, Ob0); Ob1 = fmaf(wb, (float)xb.y, Ob1);
    pA = pC; pB = pD; pC = p4; pD = p5;
  }
  float s = sa + sb;
  float O0 = Oa0 + Ob0, O1 = Oa1 + Ob1;
  float inv = 1.f / s;
  float o0 = O0 * inv + bias[f0];
  float o1 = O1 * inv + bias[f0 + 1];
  if (xres) {
    unsigned rs = xres[(size_t)v * 64 + lane];
    o0 += h2f_lo(rs);
    o1 += h2f_hi(rs);
  }
  float sum = o0 + o1, sq = o0 * o0 + o1 * o1;
  #pragma unroll
  for (int d2 = 1; d2 < 64; d2 <<= 1) {
    sum += __shfl_xor(sum, d2);
    sq += __shfl_xor(sq, d2);
  }
  float mu = sum * (1.f / 128.f);
  float var = sq * (1.f / 128.f) - mu * mu;
  float rstd = rsqrtf(var + 1e-5f);
  float y0 = fmaxf((o0 - mu) * rstd * lng[f0] + lnb[f0], 0.f);
  float y1 = fmaxf((o1 - mu) * rstd * lng[f0 + 1] + lnb[f0 + 1], 0.f);
  if (yf32) {
    *(float2*)(yf32 + (size_t)v * 128 + f0) = make_float2(y0, y1);
  } else {
    ybf[(size_t)v * 64 + lane] = packh(y0, y1);
  }
}

// ---------------- launch ----------------
extern "C" void kernel_launch(void* const* d_in, const int* in_sizes, int n_in,
                              void* d_out, int out_size, void* d_ws, size_t ws_size,
                              hipStream_t stream) {
  (void)n_in; (void)out_size; (void)ws_size;
  const int* node_types = (const int*)d_in[0];
  const int* edge_index = (const int*)d_in[1];
  const float* emb = (const float*)d_in[2];
  const float* Wl0 = (const float*)d_in[3];
  const float* Wr0 = (const float*)d_in[4];
  const float* att0 = (const float*)d_in[5];
  const float* b0 = (const float*)d_in[6];
  const float* Wl1 = (const float*)d_in[7];
  const float* Wr1 = (const float*)d_in[8];
  const float* att1 = (const float*)d_in[9];
  const float* b1 = (const float*)d_in[10];
  const float* Wl2 = (const float*)d_in[11];
  const float* Wr2 = (const float*)d_in[12];
  const float* att2 = (const float*)d_in[13];
  const float* b2 = (const float*)d_in[14];
  const float* Wl3 = (const float*)d_in[15];
  const float* Wr3 = (const float*)d_in[16];
  const float* att3 = (const float*)d_in[17];
  const float* b3 = (const float*)d_in[18];
  const float* lng = (const float*)d_in[19];
  const float* lnb = (const float*)d_in[20];

  int n = in_sizes[0];
  int e = in_sizes[1] / 2;
  const int* srcp = edge_index;
  const int* dstp = edge_index + e;
  int nblocks = (n + 255) / 256;

  // workspace carve (256-byte aligned chunks)
  char* wsp = (char*)d_ws;
  size_t ofs = 0;
  int* deg = (int*)(wsp + ofs); ofs += (((size_t)n * 4) + 255) & ~(size_t)255;
  int* off = (int*)(wsp + ofs); ofs += (((size_t)(n + 1) * 4) + 255) & ~(size_t)255;
  int* csr = (int*)(wsp + ofs); ofs += (((size_t)(e + n) * 4) + 255) & ~(size_t)255;
  int* bsum = (int*)(wsp + ofs); ofs += (((size_t)nblocks * 4) + 255) & ~(size_t)255;
  unsigned* xlb = (unsigned*)(wsp + ofs); ofs += (((size_t)n * 64 * 4) + 255) & ~(size_t)255;
  unsigned* xrb = (unsigned*)(wsp + ofs); ofs += (((size_t)n * 64 * 4) + 255) & ~(size_t)255;
  unsigned* xcur = (unsigned*)(wsp + ofs); ofs += (((size_t)n * 64 * 4) + 255) & ~(size_t)255;
  unsigned short* bp = (unsigned short*)(wsp + ofs); ofs += 3 * 65536;
  unsigned* tlb = (unsigned*)(wsp + ofs); ofs += 1024;
  float* trf = (float*)(wsp + ofs); ofs += 2048;
  int* pos = deg;  // deg dead after scan; reuse as fill cursor

  // CSR build (graph identical across all 4 layers) + weight pack (independent)
  (void)hipMemsetAsync(deg, 0, (size_t)n * 4, stream);
  k_hist<<<(e + 255) / 256, 256, 0, stream>>>(dstp, deg, e);
  k_pack3<<<385, 256, 0, stream>>>(Wl1, Wr1, Wl2, Wr2, Wl3, Wr3,
                                   emb, Wl0, Wr0, bp, tlb, trf);
  k_scan1<<<nblocks, 256, 0, stream>>>(deg, off, bsum, n);
  k_scan2<<<1, 256, 0, stream>>>(bsum, off, nblocks, n);
  k_scan3<<<nblocks, 256, 0, stream>>>(off, bsum, pos, csr, n);
  k_fill<<<(e + 255) / 256, 256, 0, stream>>>(srcp, dstp, pos, csr, e);

  int aggBlocks = (n * 64 + 255) / 256;  // one wave per node

  // layer 0: type-table aggregation (ballot histogram; writes f16 xcur)
  k_agg0<<<aggBlocks, 256, 0, stream>>>(off, csr, node_types, tlb, trf,
                                        att0, b0, lng, lnb, xcur, n);

  int nstrips = (n + 15) / 16;
  int gemmBlocks = (nstrips + 3) / 4;

  // layer 1
  k_gemm<<<gemmBlocks, 256, 0, stream>>>(xcur, bp, xlb, xrb, nstrips, n);
  k_agg<<<aggBlocks, 256, 0, stream>>>(off, csr, xlb, xrb, att1, b1, xcur,
                                       lng + 128, lnb + 128, xcur, (float*)0, n, 0);
  // layer 2
  k_gemm<<<gemmBlocks, 256, 0, stream>>>(xcur, bp + 32768, xlb, xrb, nstrips, n);
  k_agg<<<aggBlocks, 256, 0, stream>>>(off, csr, xlb, xrb, att2, b2, xcur,
                                       lng + 256, lnb + 256, xcur, (float*)0, n, 0);
  // layer 3 (single head, wide reduce; f32 output to d_out)
  k_gemm<<<gemmBlocks, 256, 0, stream>>>(xcur, bp + 65536, xlb, xrb, nstrips, n);
  k_agg<<<aggBlocks, 256, 0, stream>>>(off, csr, xlb, xrb, att3, b3, xcur,
                                       lng + 384, lnb + 384, (unsigned*)0, (float*)d_out, n, 1);
}

// Round 16
// 408.747 us; speedup vs baseline: 1.4895x; 1.0128x over previous
//
#include <hip/hip_runtime.h>

// Harness-provided kernel symbol kept (not required to do work).
__global__ void GraphEncoder_20555713479231_kernel() {}

using hfrag8 = __attribute__((ext_vector_type(8))) _Float16;  // 8 f16 (4 VGPRs)
using facc4  = __attribute__((ext_vector_type(4))) float;     // 4 fp32 acc
using h2     = __attribute__((ext_vector_type(2))) _Float16;  // packed f16 pair

__device__ __forceinline__ unsigned short f2h_bits(float f) {
  union { _Float16 h; unsigned short u; } c;
  c.h = (_Float16)f;
  return c.u;
}
__device__ __forceinline__ unsigned packh(float a, float b) {
  return (unsigned)f2h_bits(a) | ((unsigned)f2h_bits(b) << 16);
}
__device__ __forceinline__ h2 u2h(unsigned u) {
  union { unsigned u; h2 h; } c;
  c.u = u;
  return c.h;
}
__device__ __forceinline__ unsigned h22u(h2 h) {
  union { h2 h; unsigned u; } c;
  c.h = h;
  return c.u;
}
__device__ __forceinline__ float h2f_lo(unsigned u) { return (float)u2h(u).x; }
__device__ __forceinline__ float h2f_hi(unsigned u) { return (float)u2h(u).y; }

// ---------------- CSR build ----------------
__global__ __launch_bounds__(256) void k_hist(const int* __restrict__ dst,
                                              int* __restrict__ deg, int e) {
  int i = blockIdx.x * blockDim.x + threadIdx.x;
  if (i < e) atomicAdd(&deg[dst[i]], 1);
}

// parallel scan pass 1: per-block exclusive scan of (deg[i]+1); block totals to bsum
__global__ __launch_bounds__(256) void k_scan1(const int* __restrict__ deg,
                                               int* __restrict__ off,
                                               int* __restrict__ bsum, int n) {
  __shared__ int wsum[4];
  int tid = threadIdx.x;
  int gid = blockIdx.x * 256 + tid;
  int lane = tid & 63, wid = tid >> 6;
  int v = (gid < n) ? (deg[gid] + 1) : 0;
  int x = v;
  #pragma unroll
  for (int d = 1; d < 64; d <<= 1) {
    int t = __shfl_up(x, d);
    if (lane >= d) x += t;
  }
  if (lane == 63) wsum[wid] = x;
  __syncthreads();
  int wpre = 0;
  for (int k = 0; k < wid; ++k) wpre += wsum[k];
  if (gid < n) off[gid] = wpre + x - v;
  if (tid == 0) {
    int t = 0;
    #pragma unroll
    for (int k = 0; k < 4; ++k) t += wsum[k];
    bsum[blockIdx.x] = t;
  }
}

// pass 2: single block scans block sums (nb <= 256) exclusive; total -> off[n]
__global__ __launch_bounds__(256) void k_scan2(int* __restrict__ bsum,
                                               int* __restrict__ off, int nb, int n) {
  __shared__ int wsum[4];
  int tid = threadIdx.x;
  int lane = tid & 63, wid = tid >> 6;
  int v = (tid < nb) ? bsum[tid] : 0;
  int x = v;
  #pragma unroll
  for (int d = 1; d < 64; d <<= 1) {
    int t = __shfl_up(x, d);
    if (lane >= d) x += t;
  }
  if (lane == 63) wsum[wid] = x;
  __syncthreads();
  int wpre = 0;
  for (int k = 0; k < wid; ++k) wpre += wsum[k];
  if (tid < nb) bsum[tid] = wpre + x - v;
  if (tid == 0) {
    int t = 0;
    #pragma unroll
    for (int k = 0; k < 4; ++k) t += wsum[k];
    off[n] = t;
  }
}

// pass 3: add block prefix; also init self-loop slot and fill cursor (fused initpos)
__global__ __launch_bounds__(256) void k_scan3(int* __restrict__ off,
                                               const int* __restrict__ bsum,
                                               int* __restrict__ pos,
                                               int* __restrict__ csr, int n) {
  int gid = blockIdx.x * 256 + threadIdx.x;
  if (gid < n) {
    int o = off[gid] + bsum[blockIdx.x];
    off[gid] = o;
    csr[o] = gid;  // self-loop occupies first slot
    pos[gid] = o + 1;
  }
}

__global__ __launch_bounds__(256) void k_fill(const int* __restrict__ src,
                                              const int* __restrict__ dst,
                                              int* __restrict__ pos,
                                              int* __restrict__ csr, int e) {
  int i = blockIdx.x * blockDim.x + threadIdx.x;
  if (i < e) {
    int d = dst[i];
    int p = atomicAdd(&pos[d], 1);
    csr[p] = src[i];
  }
}

// ---------------- pack weights (3 layers) + layer-0 tables + bit-packed types ------
// blocks 0..383: bp[layer][((t*16+ct)*64+lane)*8+j] =
//   W[k=t*32+(lane>>4)*8+j][c=ct*16+(lane&15)], c<128->Wl else Wr (f16)
// block 384: emb @ W0 tables -> tlb (f16 pairs), trf (f32)
// blocks 385..: ptypes[i] packs types[16i..16i+15] at 2 bits each (12.5 KB, L1-hot)
__global__ __launch_bounds__(256)
void k_pack3(const float* __restrict__ wl1, const float* __restrict__ wr1,
             const float* __restrict__ wl2, const float* __restrict__ wr2,
             const float* __restrict__ wl3, const float* __restrict__ wr3,
             const float* __restrict__ emb,
             const float* __restrict__ wl0, const float* __restrict__ wr0,
             const int* __restrict__ types, int n,
             unsigned short* __restrict__ bp,
             unsigned* __restrict__ tlb, float* __restrict__ trf,
             unsigned* __restrict__ ptypes) {
  int b = blockIdx.x;
  if (b < 384) {
    int idx = b * 256 + threadIdx.x;  // 0..98303
    int layer = idx >> 15;
    int r = idx & 32767;
    int j = r & 7, lane = (r >> 3) & 63, ct = (r >> 9) & 15, t = r >> 13;
    int k = t * 32 + (lane >> 4) * 8 + j;
    int c = ct * 16 + (lane & 15);
    const float* wl = (layer == 0) ? wl1 : ((layer == 1) ? wl2 : wl3);
    const float* wr = (layer == 0) ? wr1 : ((layer == 1) ? wr2 : wr3);
    float v = (c < 128) ? wl[k * 128 + c] : wr[k * 128 + (c - 128)];
    bp[idx] = f2h_bits(v);
  } else if (b == 384) {
    int tid = threadIdx.x;
    if (tid >= 192) return;
    int row = tid >> 6, cp = tid & 63, c0 = cp * 2;
    float al0 = 0.f, al1 = 0.f, ar0 = 0.f, ar1 = 0.f;
    #pragma unroll
    for (int k = 0; k < 16; ++k) {
      float ev = emb[row * 16 + k];
      al0 += ev * wl0[k * 128 + c0];
      al1 += ev * wl0[k * 128 + c0 + 1];
      ar0 += ev * wr0[k * 128 + c0];
      ar1 += ev * wr0[k * 128 + c0 + 1];
    }
    tlb[row * 64 + cp] = packh(al0, al1);
    *(float2*)(trf + row * 128 + c0) = make_float2(ar0, ar1);
  } else {
    int i = (b - 385) * 256 + threadIdx.x;
    int npk = (n + 15) >> 4;
    if (i < npk) {
      unsigned pw = 0;
      #pragma unroll
      for (int j = 0; j < 16; ++j) {
        int u = i * 16 + j;
        int ty = (u < n) ? (types[u] & 3) : 3;
        pw |= ((unsigned)ty) << (2 * j);
      }
      ptypes[i] = pw;
    }
  }
}

// ---------------- layer-0 aggregation via neighbor-type histogram ----------------
// type gather served from 12.5 KB bit-packed table (L1-resident)
__global__ __launch_bounds__(256)
void k_agg0(const int* __restrict__ off, const int* __restrict__ csr,
            const unsigned* __restrict__ ptypes,
            const unsigned* __restrict__ tlb, const float* __restrict__ trf,
            const float* __restrict__ att, const float* __restrict__ bias,
            const float* __restrict__ lng, const float* __restrict__ lnb,
            unsigned* __restrict__ yout, int n) {
  int v = (blockIdx.x * blockDim.x + threadIdx.x) >> 6;
  int lane = threadIdx.x & 63;
  if (v >= n) return;
  v = __builtin_amdgcn_readfirstlane(v);
  int beg = off[v], end = off[v + 1];
  int c0 = 0, c1 = 0, c2 = 0;
  for (int base = beg; base < end; base += 64) {
    int e = base + lane;
    bool act = e < end;
    int u = act ? csr[e] : 0;
    unsigned pw = ptypes[u >> 4];
    int ty = act ? (int)((pw >> ((u & 15) * 2)) & 3) : 3;
    c0 += __popcll(__ballot(ty == 0));
    c1 += __popcll(__ballot(ty == 1));
    c2 += __popcll(__ballot(ty == 2));
  }
  float cnt[3] = {(float)c0, (float)c1, (float)c2};
  int f0 = lane * 2;
  unsigned pwv = ptypes[v >> 4];
  int tyv = (int)((pwv >> ((v & 15) * 2)) & 3);
  float2 xrv = *(const float2*)(trf + tyv * 128 + f0);
  float a0 = att[f0], a1 = att[f0 + 1];
  float s = 0.f, O0 = 0.f, O1 = 0.f;
  #pragma unroll
  for (int ty = 0; ty < 3; ++ty) {
    unsigned p = tlb[ty * 64 + lane];
    float x0 = h2f_lo(p), x1 = h2f_hi(p);
    float t0 = x0 + xrv.x; t0 = t0 > 0.f ? t0 : 0.2f * t0;
    float t1 = x1 + xrv.y; t1 = t1 > 0.f ? t1 : 0.2f * t1;
    float c = t0 * a0 + t1 * a1;
    c += __shfl_xor(c, 1);
    c += __shfl_xor(c, 2);
    c += __shfl_xor(c, 4);
    c += __shfl_xor(c, 8);
    float w = cnt[ty] * __expf(c);
    s += w;
    O0 = fmaf(w, x0, O0);
    O1 = fmaf(w, x1, O1);
  }
  float inv = 1.f / s;
  float o0 = O0 * inv + bias[f0];
  float o1 = O1 * inv + bias[f0 + 1];
  float sum = o0 + o1, sq = o0 * o0 + o1 * o1;
  #pragma unroll
  for (int d2 = 1; d2 < 64; d2 <<= 1) {
    sum += __shfl_xor(sum, d2);
    sq += __shfl_xor(sq, d2);
  }
  float mu = sum * (1.f / 128.f);
  float var = sq * (1.f / 128.f) - mu * mu;
  float rstd = rsqrtf(var + 1e-5f);
  float y0 = fmaxf((o0 - mu) * rstd * lng[f0] + lnb[f0], 0.f);
  float y1 = fmaxf((o1 - mu) * rstd * lng[f0 + 1] + lnb[f0 + 1], 0.f);
  yout[(size_t)v * 64 + lane] = packh(y0, y1);
}

// ---------------- GEMM (MFMA f16): x(Nx128 f16 packed) @ [Wl|Wr] -> xl, xr (f16 packed) ----
// One wave per 16-row strip; 64x mfma_f32_16x16x32_f16; no LDS.
__global__ __launch_bounds__(256)
void k_gemm(const unsigned* __restrict__ x, const unsigned short* __restrict__ bp,
            unsigned* __restrict__ xlo, unsigned* __restrict__ xro, int nstrips, int n) {
  int wave = (blockIdx.x * 256 + threadIdx.x) >> 6;
  int lane = threadIdx.x & 63;
  if (wave >= nstrips) return;
  int r0 = wave * 16;
  int row = r0 + (lane & 15);
  if (row >= n) row = n - 1;
  int quad = lane >> 4;
  const unsigned* ap = x + (size_t)row * 64;
  hfrag8 a[4];
  #pragma unroll
  for (int t = 0; t < 4; ++t) a[t] = *(const hfrag8*)(ap + t * 16 + quad * 4);
  unsigned short* xloS = (unsigned short*)xlo;
  unsigned short* xroS = (unsigned short*)xro;
  int rbase = r0 + quad * 4;
  #pragma unroll
  for (int ct = 0; ct < 16; ++ct) {
    facc4 acc = {0.f, 0.f, 0.f, 0.f};
    #pragma unroll
    for (int t = 0; t < 4; ++t) {
      hfrag8 b = *(const hfrag8*)(bp + (size_t)(((t * 16 + ct) * 64 + lane) * 8));
      acc = __builtin_amdgcn_mfma_f32_16x16x32_f16(a[t], b, acc, 0, 0, 0);
    }
    int col = (ct & 7) * 16 + (lane & 15);
    unsigned short* dstp = (ct < 8) ? xloS : xroS;
    #pragma unroll
    for (int i = 0; i < 4; ++i) {
      int r = rbase + i;
      if (r < n) dstp[(size_t)r * 128 + col] = f2h_bits(acc[i]);
    }
  }
}

// ---------------- fused aggregate + bias + residual + LN + ReLU (f16 packed) ----------
// one wave per dst node; lane owns features 2*lane, 2*lane+1; activations f16 pairs.
// Packed logit pair rides one shuffle tree; O accumulated in packed f16 (pk_fma).
__global__ __launch_bounds__(256)
void k_agg(const int* __restrict__ off, const int* __restrict__ csr,
           const unsigned* __restrict__ xl, const unsigned* __restrict__ xr,
           const float* __restrict__ att, const float* __restrict__ bias,
           const unsigned* __restrict__ xres,
           const float* __restrict__ lng, const float* __restrict__ lnb,
           unsigned* __restrict__ ybf, float* __restrict__ yf32, int n, int wide) {
  int v = (blockIdx.x * blockDim.x + threadIdx.x) >> 6;
  int lane = threadIdx.x & 63;
  if (v >= n) return;
  v = __builtin_amdgcn_readfirstlane(v);
  int f0 = lane * 2;
  h2 a2;
  a2.x = (_Float16)att[f0];
  a2.y = (_Float16)att[f0 + 1];
  h2 r2 = u2h(xr[(size_t)v * 64 + lane]);
  h2 k02 = {(_Float16)0.2f, (_Float16)0.2f};
  int beg = off[v], end = off[v + 1];
  int last = end - 1;
  const unsigned* xlp = xl + lane;  // row r at xlp[r*64]
  int iA = csr[beg];
  int iB = csr[min(beg + 1, last)];
  int iC = csr[min(beg + 2, last)];
  int iD = csr[min(beg + 3, last)];
  unsigned pA = xlp[(size_t)iA * 64];
  unsigned pB = xlp[(size_t)iB * 64];
  unsigned pC = xlp[(size_t)iC * 64];
  unsigned pD = xlp[(size_t)iD * 64];
  float sa = 0.f, sb = 0.f;
  h2 Oa = {(_Float16)0.f, (_Float16)0.f};
  h2 Ob = {(_Float16)0.f, (_Float16)0.f};
  for (int e = beg; e < end; e += 2) {
    int i4 = csr[min(e + 4, last)];
    int i5 = csr[min(e + 5, last)];
    unsigned p4 = xlp[(size_t)i4 * 64];
    unsigned p5 = xlp[(size_t)i5 * 64];
    h2 xa = u2h(pA), xb = u2h(pB);
    h2 ta = xa + r2;
    h2 tb = xb + r2;
    h2 la = __builtin_elementwise_max(ta, ta * k02);  // pk leaky relu
    h2 lb = __builtin_elementwise_max(tb, tb * k02);
    h2 da = la * a2;
    h2 db = lb * a2;
    h2 cp;
    cp.x = da.x + da.y;  // edge A partial logit
    cp.y = db.x + db.y;  // edge B partial logit
    unsigned cu = h22u(cp);
    cu = h22u(u2h(cu) + u2h((unsigned)__shfl_xor((int)cu, 1)));
    cu = h22u(u2h(cu) + u2h((unsigned)__shfl_xor((int)cu, 2)));
    cu = h22u(u2h(cu) + u2h((unsigned)__shfl_xor((int)cu, 4)));
    cu = h22u(u2h(cu) + u2h((unsigned)__shfl_xor((int)cu, 8)));
    if (wide) {
      cu = h22u(u2h(cu) + u2h((unsigned)__shfl_xor((int)cu, 16)));
      cu = h22u(u2h(cu) + u2h((unsigned)__shfl_xor((int)cu, 32)));
    }
    h2 cf = u2h(cu);
    float wa = __expf((float)cf.x);
    float wb = (e + 1 < end) ? __expf((float)cf.y) : 0.f;
    sa += wa;
    sb += wb;
    _Float16 wah = (_Float16)wa;
    _Float16 wbh = (_Float16)wb;
    h2 wa2 = {wah, wah};
    h2 wb2 = {wbh, wbh};
    Oa = wa2 * xa + Oa;  // v_pk_fma_f16
    Ob = wb2 * xb + Ob;
    pA = pC; pB = pD; pC = p4; pD = p5;
  }
  float s = sa + sb;
  float O0 = (float)Oa.x + (float)Ob.x;
  float O1 = (float)Oa.y + (float)Ob.y;
  float inv = 1.f / s;
  float o0 = O0 * inv + bias[f0];
  float o1 = O1 * inv + bias[f0 + 1];
  if (xres) {
    unsigned rs = xres[(size_t)v * 64 + lane];
    o0 += h2f_lo(rs);
    o1 += h2f_hi(rs);
  }
  float sum = o0 + o1, sq = o0 * o0 + o1 * o1;
  #pragma unroll
  for (int d2 = 1; d2 < 64; d2 <<= 1) {
    sum += __shfl_xor(sum, d2);
    sq += __shfl_xor(sq, d2);
  }
  float mu = sum * (1.f / 128.f);
  float var = sq * (1.f / 128.f) - mu * mu;
  float rstd = rsqrtf(var + 1e-5f);
  float y0 = fmaxf((o0 - mu) * rstd * lng[f0] + lnb[f0], 0.f);
  float y1 = fmaxf((o1 - mu) * rstd * lng[f0 + 1] + lnb[f0 + 1], 0.f);
  if (yf32) {
    *(float2*)(yf32 + (size_t)v * 128 + f0) = make_float2(y0, y1);
  } else {
    ybf[(size_t)v * 64 + lane] = packh(y0, y1);
  }
}

// ---------------- launch ----------------
extern "C" void kernel_launch(void* const* d_in, const int* in_sizes, int n_in,
                              void* d_out, int out_size, void* d_ws, size_t ws_size,
                              hipStream_t stream) {
  (void)n_in; (void)out_size; (void)ws_size;
  const int* node_types = (const int*)d_in[0];
  const int* edge_index = (const int*)d_in[1];
  const float* emb = (const float*)d_in[2];
  const float* Wl0 = (const float*)d_in[3];
  const float* Wr0 = (const float*)d_in[4];
  const float* att0 = (const float*)d_in[5];
  const float* b0 = (const float*)d_in[6];
  const float* Wl1 = (const float*)d_in[7];
  const float* Wr1 = (const float*)d_in[8];
  const float* att1 = (const float*)d_in[9];
  const float* b1 = (const float*)d_in[10];
  const float* Wl2 = (const float*)d_in[11];
  const float* Wr2 = (const float*)d_in[12];
  const float* att2 = (const float*)d_in[13];
  const float* b2 = (const float*)d_in[14];
  const float* Wl3 = (const float*)d_in[15];
  const float* Wr3 = (const float*)d_in[16];
  const float* att3 = (const float*)d_in[17];
  const float* b3 = (const float*)d_in[18];
  const float* lng = (const float*)d_in[19];
  const float* lnb = (const float*)d_in[20];

  int n = in_sizes[0];
  int e = in_sizes[1] / 2;
  const int* srcp = edge_index;
  const int* dstp = edge_index + e;
  int nblocks = (n + 255) / 256;

  // workspace carve (256-byte aligned chunks)
  char* wsp = (char*)d_ws;
  size_t ofs = 0;
  int* deg = (int*)(wsp + ofs); ofs += (((size_t)n * 4) + 255) & ~(size_t)255;
  int* off = (int*)(wsp + ofs); ofs += (((size_t)(n + 1) * 4) + 255) & ~(size_t)255;
  int* csr = (int*)(wsp + ofs); ofs += (((size_t)(e + n) * 4) + 255) & ~(size_t)255;
  int* bsum = (int*)(wsp + ofs); ofs += (((size_t)nblocks * 4) + 255) & ~(size_t)255;
  unsigned* xlb = (unsigned*)(wsp + ofs); ofs += (((size_t)n * 64 * 4) + 255) & ~(size_t)255;
  unsigned* xrb = (unsigned*)(wsp + ofs); ofs += (((size_t)n * 64 * 4) + 255) & ~(size_t)255;
  unsigned* xcur = (unsigned*)(wsp + ofs); ofs += (((size_t)n * 64 * 4) + 255) & ~(size_t)255;
  unsigned short* bp = (unsigned short*)(wsp + ofs); ofs += 3 * 65536;
  unsigned* tlb = (unsigned*)(wsp + ofs); ofs += 1024;
  float* trf = (float*)(wsp + ofs); ofs += 2048;
  unsigned* ptypes = (unsigned*)(wsp + ofs); ofs += ((((size_t)(n + 15) / 16) * 4) + 255) & ~(size_t)255;
  int* pos = deg;  // deg dead after scan; reuse as fill cursor

  // CSR build (graph identical across all 4 layers) + weight/type pack (independent)
  (void)hipMemsetAsync(deg, 0, (size_t)n * 4, stream);
  k_hist<<<(e + 255) / 256, 256, 0, stream>>>(dstp, deg, e);
  int npk = (n + 15) / 16;
  int packGrid = 385 + (npk + 255) / 256;
  k_pack3<<<packGrid, 256, 0, stream>>>(Wl1, Wr1, Wl2, Wr2, Wl3, Wr3,
                                        emb, Wl0, Wr0, node_types, n,
                                        bp, tlb, trf, ptypes);
  k_scan1<<<nblocks, 256, 0, stream>>>(deg, off, bsum, n);
  k_scan2<<<1, 256, 0, stream>>>(bsum, off, nblocks, n);
  k_scan3<<<nblocks, 256, 0, stream>>>(off, bsum, pos, csr, n);
  k_fill<<<(e + 255) / 256, 256, 0, stream>>>(srcp, dstp, pos, csr, e);

  int aggBlocks = (n * 64 + 255) / 256;  // one wave per node

  // layer 0: type-table aggregation (ballot histogram from packed types)
  k_agg0<<<aggBlocks, 256, 0, stream>>>(off, csr, ptypes, tlb, trf,
                                        att0, b0, lng, lnb, xcur, n);

  int nstrips = (n + 15) / 16;
  int gemmBlocks = (nstrips + 3) / 4;

  // layer 1
  k_gemm<<<gemmBlocks, 256, 0, stream>>>(xcur, bp, xlb, xrb, nstrips, n);
  k_agg<<<aggBlocks, 256, 0, stream>>>(off, csr, xlb, xrb, att1, b1, xcur,
                                       lng + 128, lnb + 128, xcur, (float*)0, n, 0);
  // layer 2
  k_gemm<<<gemmBlocks, 256, 0, stream>>>(xcur, bp + 32768, xlb, xrb, nstrips, n);
  k_agg<<<aggBlocks, 256, 0, stream>>>(off, csr, xlb, xrb, att2, b2, xcur,
                                       lng + 256, lnb + 256, xcur, (float*)0, n, 0);
  // layer 3 (single head, wide reduce; f32 output to d_out)
  k_gemm<<<gemmBlocks, 256, 0, stream>>>(xcur, bp + 65536, xlb, xrb, nstrips, n);
  k_agg<<<aggBlocks, 256, 0, stream>>>(off, csr, xlb, xrb, att3, b3, xcur,
                                       lng + 384, lnb + 384, (unsigned*)0, (float*)d_out, n, 1);
}